// Round 1
// baseline (2958.021 us; speedup 1.0000x reference)
//
#include <hip/hip_runtime.h>
#include <math.h>

#define DD 128
#define NEG_SLOPE 0.2f
#define SOFT_EPS 1e-16f

// ---- monotonic float<->unsigned mapping for atomicMax on floats ----
__device__ __forceinline__ unsigned mapf(float f) {
    unsigned u = __float_as_uint(f);
    return (u & 0x80000000u) ? ~u : (u | 0x80000000u);
}
__device__ __forceinline__ float unmapf(unsigned m) {
    return (m & 0x80000000u) ? __uint_as_float(m ^ 0x80000000u)
                             : __uint_as_float(~m);
}
__device__ __forceinline__ float lrelu(float v) {
    return v >= 0.f ? v : NEG_SLOPE * v;
}

// ---- K1: h = x @ W  (N x 128 @ 128 x 128, fp32 vector ALU) ----
// block = 256 threads; tile = 64 rows x 128 cols; per-thread 8 rows x 4 cols
__global__ __launch_bounds__(256) void k_gemm(
        const float* __restrict__ x, const float* __restrict__ W,
        float* __restrict__ h, int N) {
    __shared__ float sX[64 * 32];    // 8 KB
    __shared__ float sW[32 * DD];    // 16 KB
    const int tid = threadIdx.x;
    const int cg = tid & 31;         // col group (4 cols)
    const int rg = tid >> 5;         // row group (8 rows)
    const int rbase = blockIdx.x * 64;

    float4 acc[8];
#pragma unroll
    for (int r = 0; r < 8; ++r) acc[r] = make_float4(0.f, 0.f, 0.f, 0.f);

    for (int kc = 0; kc < 4; ++kc) {
        const int kbase = kc * 32;
        // stage x chunk: 64 x 32 floats, 2 float4 per thread
#pragma unroll
        for (int i = 0; i < 2; ++i) {
            int lin = tid + i * 256;        // float4 index (512 total)
            int row = lin >> 3;             // 8 float4 per row
            int k4  = lin & 7;
            int grow = rbase + row;
            float4 v = make_float4(0.f, 0.f, 0.f, 0.f);
            if (grow < N) v = *(const float4*)&x[grow * DD + kbase + k4 * 4];
            *(float4*)&sX[row * 32 + k4 * 4] = v;
        }
        // stage W chunk: 32 x 128 floats, 4 float4 per thread
#pragma unroll
        for (int i = 0; i < 4; ++i) {
            int lin = tid + i * 256;        // float4 index (1024 total)
            int krow = lin >> 5;            // 32 float4 per row
            int c4 = lin & 31;
            *(float4*)&sW[krow * DD + c4 * 4] =
                *(const float4*)&W[(kbase + krow) * DD + c4 * 4];
        }
        __syncthreads();
#pragma unroll
        for (int kk = 0; kk < 32; ++kk) {
            float4 w = *(float4*)&sW[kk * DD + cg * 4];
#pragma unroll
            for (int r = 0; r < 8; ++r) {
                float xv = sX[(rg * 8 + r) * 32 + kk];
                acc[r].x += xv * w.x; acc[r].y += xv * w.y;
                acc[r].z += xv * w.z; acc[r].w += xv * w.w;
            }
        }
        __syncthreads();
    }
#pragma unroll
    for (int r = 0; r < 8; ++r) {
        int grow = rbase + rg * 8 + r;
        if (grow < N) *(float4*)&h[grow * DD + cg * 4] = acc[r];
    }
}

// ---- K2: per-node a_src/a_dst + init segment-max with self-loop alpha ----
// one wave (64 lanes) per node
__global__ __launch_bounds__(256) void k_node_scores(
        const float* __restrict__ h,
        const float* __restrict__ att_src, const float* __restrict__ att_dst,
        float* __restrict__ a_src, float* __restrict__ a_dst,
        unsigned* __restrict__ amax_u, int N) {
    int node = (blockIdx.x * 256 + threadIdx.x) >> 6;
    int lane = threadIdx.x & 63;
    if (node >= N) return;
    float2 hv = *(const float2*)&h[node * DD + lane * 2];
    float2 as = *(const float2*)&att_src[lane * 2];
    float2 ad = *(const float2*)&att_dst[lane * 2];
    float s = hv.x * as.x + hv.y * as.y;
    float d = hv.x * ad.x + hv.y * ad.y;
#pragma unroll
    for (int off = 32; off; off >>= 1) {
        s += __shfl_down(s, off);
        d += __shfl_down(d, off);
    }
    if (lane == 0) {
        a_src[node] = s;
        a_dst[node] = d;
        amax_u[node] = mapf(lrelu(s + d));   // self-loop score seeds the max
    }
}

// ---- K3: per-edge raw score + atomic segment max ----
__global__ __launch_bounds__(256) void k_edge_alpha(
        const int* __restrict__ ei,
        const float* __restrict__ a_src, const float* __restrict__ a_dst,
        float* __restrict__ ealpha, unsigned* __restrict__ amax_u, int E) {
    int e = blockIdx.x * 256 + threadIdx.x;
    if (e >= E) return;
    int s = ei[e], d = ei[E + e];
    float al = lrelu(a_src[s] + a_dst[d]);
    ealpha[e] = al;
    atomicMax(&amax_u[d], mapf(al));
}

// ---- K4: unmap amax to float in place; init denom with self-loop exp ----
__global__ __launch_bounds__(256) void k_node_max_fin(
        const float* __restrict__ a_src, const float* __restrict__ a_dst,
        unsigned* __restrict__ amax_u, float* __restrict__ amax_f,
        float* __restrict__ denom, float* __restrict__ selfex, int N) {
    int i = blockIdx.x * 256 + threadIdx.x;
    if (i >= N) return;
    float m = unmapf(amax_u[i]);
    amax_f[i] = m;                      // aliases amax_u buffer, in-place ok
    float al = lrelu(a_src[i] + a_dst[i]);
    float es = __expf(al - m);
    selfex[i] = es;
    denom[i] = es;
}

// ---- K5: per-edge exp + atomic denom accumulation ----
__global__ __launch_bounds__(256) void k_edge_exp(
        const int* __restrict__ ei, const float* __restrict__ amax_f,
        float* __restrict__ ealpha, float* __restrict__ denom, int E) {
    int e = blockIdx.x * 256 + threadIdx.x;
    if (e >= E) return;
    int d = ei[E + e];
    float ex = __expf(ealpha[e] - amax_f[d]);
    ealpha[e] = ex;                     // overwrite alpha with exp in place
    unsafeAtomicAdd(&denom[d], ex);
}

// ---- K6: initialize out with the self-loop contribution ----
// 32 threads per node (float4 each)
__global__ __launch_bounds__(256) void k_self_out(
        const float* __restrict__ h, const float* __restrict__ selfex,
        const float* __restrict__ denom, float* __restrict__ out, int N) {
    int t = blockIdx.x * 256 + threadIdx.x;
    int i = t >> 5, c = t & 31;
    if (i >= N) return;
    float coef = selfex[i] / (denom[i] + SOFT_EPS);
    float4 hv = *(const float4*)&h[i * DD + c * 4];
    float4 o = make_float4(hv.x * coef, hv.y * coef, hv.z * coef, hv.w * coef);
    *(float4*)&out[i * DD + c * 4] = o;
}

// ---- K7: per-edge weighted scatter-add (32 threads / edge) ----
__global__ __launch_bounds__(256) void k_edge_scatter(
        const int* __restrict__ ei, const float* __restrict__ h,
        const float* __restrict__ ealpha, const float* __restrict__ denom,
        float* __restrict__ out, int E) {
    int t = blockIdx.x * 256 + threadIdx.x;
    int e = t >> 5, c = t & 31;
    if (e >= E) return;
    int s = ei[e], d = ei[E + e];
    float coef = ealpha[e] / (denom[d] + SOFT_EPS);
    float4 hv = *(const float4*)&h[s * DD + c * 4];
    float* ob = &out[d * DD + c * 4];
    unsafeAtomicAdd(ob + 0, hv.x * coef);
    unsafeAtomicAdd(ob + 1, hv.y * coef);
    unsafeAtomicAdd(ob + 2, hv.z * coef);
    unsafeAtomicAdd(ob + 3, hv.w * coef);
}

extern "C" void kernel_launch(void* const* d_in, const int* in_sizes, int n_in,
                              void* d_out, int out_size, void* d_ws, size_t ws_size,
                              hipStream_t stream) {
    const float* x       = (const float*)d_in[0];
    const int*   ei      = (const int*)d_in[1];
    const float* W       = (const float*)d_in[2];
    const float* att_src = (const float*)d_in[3];
    const float* att_dst = (const float*)d_in[4];
    float* out = (float*)d_out;

    const int N = in_sizes[0] / DD;     // 50000
    const int E = in_sizes[1] / 2;      // 1600000

    // workspace layout (floats): h | a_src | a_dst | amax | denom | selfex | ealpha
    float* ws      = (float*)d_ws;
    float* h       = ws;
    float* a_src   = h + (size_t)N * DD;
    float* a_dst   = a_src + N;
    float* amax    = a_dst + N;
    float* denom   = amax + N;
    float* selfex  = denom + N;
    float* ealpha  = selfex + N;

    k_gemm<<<(N + 63) / 64, 256, 0, stream>>>(x, W, h, N);
    k_node_scores<<<(N + 3) / 4, 256, 0, stream>>>(h, att_src, att_dst,
                                                   a_src, a_dst,
                                                   (unsigned*)amax, N);
    k_edge_alpha<<<(E + 255) / 256, 256, 0, stream>>>(ei, a_src, a_dst,
                                                      ealpha, (unsigned*)amax, E);
    k_node_max_fin<<<(N + 255) / 256, 256, 0, stream>>>(a_src, a_dst,
                                                        (unsigned*)amax, amax,
                                                        denom, selfex, N);
    k_edge_exp<<<(E + 255) / 256, 256, 0, stream>>>(ei, amax, ealpha, denom, E);
    k_self_out<<<(N * 32 + 255) / 256, 256, 0, stream>>>(h, selfex, denom, out, N);
    k_edge_scatter<<<((E * 32) + 255) / 256, 256, 0, stream>>>(ei, h, ealpha,
                                                               denom, out, E);
}

// Round 2
// 424.602 us; speedup vs baseline: 6.9666x; 6.9666x over previous
//
#include <hip/hip_runtime.h>
#include <math.h>

#define DD 128
#define NEG_SLOPE 0.2f
#define SOFT_EPS 1e-16f

__device__ __forceinline__ float lrelu(float v) {
    return v >= 0.f ? v : NEG_SLOPE * v;
}

// ---- K1: h = x @ W  (N x 128 @ 128 x 128, fp32 vector ALU) ----
__global__ __launch_bounds__(256) void k_gemm(
        const float* __restrict__ x, const float* __restrict__ W,
        float* __restrict__ h, int N) {
    __shared__ float sX[64 * 32];
    __shared__ float sW[32 * DD];
    const int tid = threadIdx.x;
    const int cg = tid & 31;
    const int rg = tid >> 5;
    const int rbase = blockIdx.x * 64;

    float4 acc[8];
#pragma unroll
    for (int r = 0; r < 8; ++r) acc[r] = make_float4(0.f, 0.f, 0.f, 0.f);

    for (int kc = 0; kc < 4; ++kc) {
        const int kbase = kc * 32;
#pragma unroll
        for (int i = 0; i < 2; ++i) {
            int lin = tid + i * 256;
            int row = lin >> 3;
            int k4  = lin & 7;
            int grow = rbase + row;
            float4 v = make_float4(0.f, 0.f, 0.f, 0.f);
            if (grow < N) v = *(const float4*)&x[grow * DD + kbase + k4 * 4];
            *(float4*)&sX[row * 32 + k4 * 4] = v;
        }
#pragma unroll
        for (int i = 0; i < 4; ++i) {
            int lin = tid + i * 256;
            int krow = lin >> 5;
            int c4 = lin & 31;
            *(float4*)&sW[krow * DD + c4 * 4] =
                *(const float4*)&W[(kbase + krow) * DD + c4 * 4];
        }
        __syncthreads();
#pragma unroll
        for (int kk = 0; kk < 32; ++kk) {
            float4 w = *(float4*)&sW[kk * DD + cg * 4];
#pragma unroll
            for (int r = 0; r < 8; ++r) {
                float xv = sX[(rg * 8 + r) * 32 + kk];
                acc[r].x += xv * w.x; acc[r].y += xv * w.y;
                acc[r].z += xv * w.z; acc[r].w += xv * w.w;
            }
        }
        __syncthreads();
    }
#pragma unroll
    for (int r = 0; r < 8; ++r) {
        int grow = rbase + rg * 8 + r;
        if (grow < N) *(float4*)&h[grow * DD + cg * 4] = acc[r];
    }
}

// ---- K2: per-node a_src/a_dst (one wave per node) ----
__global__ __launch_bounds__(256) void k_node_scores(
        const float* __restrict__ h,
        const float* __restrict__ att_src, const float* __restrict__ att_dst,
        float* __restrict__ a_src, float* __restrict__ a_dst, int N) {
    int node = (blockIdx.x * 256 + threadIdx.x) >> 6;
    int lane = threadIdx.x & 63;
    if (node >= N) return;
    float2 hv = *(const float2*)&h[(size_t)node * DD + lane * 2];
    float2 as = *(const float2*)&att_src[lane * 2];
    float2 ad = *(const float2*)&att_dst[lane * 2];
    float s = hv.x * as.x + hv.y * as.y;
    float d = hv.x * ad.x + hv.y * ad.y;
#pragma unroll
    for (int off = 32; off; off >>= 1) {
        s += __shfl_down(s, off);
        d += __shfl_down(d, off);
    }
    if (lane == 0) {
        a_src[node] = s;
        a_dst[node] = d;
    }
}

// ---- CSR build ----
__global__ __launch_bounds__(256) void k_zero(int* __restrict__ deg, int N) {
    int i = blockIdx.x * 256 + threadIdx.x;
    if (i < N) deg[i] = 0;
}

__global__ __launch_bounds__(256) void k_hist(
        const int* __restrict__ ei, int* __restrict__ deg, int E) {
    int e = blockIdx.x * 256 + threadIdx.x;
    if (e >= E) return;
    atomicAdd(&deg[ei[E + e]], 1);
}

// block scans 1024 elements (256 thr x 4); writes local-exclusive into off,
// block total into parts
__global__ __launch_bounds__(256) void k_scan1(
        const int* __restrict__ deg, int* __restrict__ off,
        int* __restrict__ parts, int N) {
    __shared__ int sm[256];
    int t = threadIdx.x;
    int base = blockIdx.x * 1024 + t * 4;
    int v[4];
    int sum = 0;
#pragma unroll
    for (int i = 0; i < 4; ++i) {
        int idx = base + i;
        v[i] = (idx < N) ? deg[idx] : 0;
        sum += v[i];
    }
    sm[t] = sum;
    __syncthreads();
    for (int ofs = 1; ofs < 256; ofs <<= 1) {
        int xv = (t >= ofs) ? sm[t - ofs] : 0;
        __syncthreads();
        sm[t] += xv;
        __syncthreads();
    }
    int run = sm[t] - sum;                 // exclusive prefix of this thread
    if (t == 255) parts[blockIdx.x] = sm[255];
#pragma unroll
    for (int i = 0; i < 4; ++i) {
        int idx = base + i;
        if (idx < N) off[idx] = run;
        run += v[i];
    }
}

// single block: exclusive scan of parts[0..nparts), nparts <= 256
__global__ __launch_bounds__(256) void k_scan2(int* __restrict__ parts, int nparts) {
    __shared__ int sm[256];
    int t = threadIdx.x;
    int v = (t < nparts) ? parts[t] : 0;
    sm[t] = v;
    __syncthreads();
    for (int ofs = 1; ofs < 256; ofs <<= 1) {
        int xv = (t >= ofs) ? sm[t - ofs] : 0;
        __syncthreads();
        sm[t] += xv;
        __syncthreads();
    }
    if (t < nparts) parts[t] = sm[t] - v;
}

// add block offsets; zero deg for reuse as fill cursor; set off[N]=E
__global__ __launch_bounds__(256) void k_scan3(
        int* __restrict__ off, const int* __restrict__ parts,
        int* __restrict__ deg, int N, int E) {
    int i = blockIdx.x * 256 + threadIdx.x;
    if (i < N) {
        off[i] += parts[i >> 10];
        deg[i] = 0;
    }
    if (i == 0) off[N] = E;
}

__global__ __launch_bounds__(256) void k_fill(
        const int* __restrict__ ei, const int* __restrict__ off,
        int* __restrict__ cur, int* __restrict__ srcs, int E) {
    int e = blockIdx.x * 256 + threadIdx.x;
    if (e >= E) return;
    int s = ei[e], d = ei[E + e];
    int pos = off[d] + atomicAdd(&cur[d], 1);
    srcs[pos] = s;
}

// ---- K-agg: one wave per dst node; softmax + gather-accumulate, no atomics ----
__global__ __launch_bounds__(256) void k_agg(
        const int* __restrict__ off, const int* __restrict__ srcs,
        const float* __restrict__ h,
        const float* __restrict__ a_src, const float* __restrict__ a_dst,
        float* __restrict__ out, int N) {
    int node = (blockIdx.x * 256 + threadIdx.x) >> 6;
    int lane = threadIdx.x & 63;
    if (node >= N) return;
    int r0 = off[node];
    int deg = off[node + 1] - r0;
    float adst = a_dst[node];
    float self_al = lrelu(a_src[node] + adst);

    // phase A: segment max (self-loop seeds)
    float m = self_al;
    for (int j = lane; j < deg; j += 64) {
        int s = srcs[r0 + j];
        m = fmaxf(m, lrelu(a_src[s] + adst));
    }
#pragma unroll
    for (int o = 32; o; o >>= 1) m = fmaxf(m, __shfl_xor(m, o));

    // phase B: denominator
    float t = 0.f;
    for (int j = lane; j < deg; j += 64) {
        int s = srcs[r0 + j];
        t += __expf(lrelu(a_src[s] + adst) - m);
    }
#pragma unroll
    for (int o = 32; o; o >>= 1) t += __shfl_xor(t, o);
    float eself = __expf(self_al - m);
    float inv = 1.f / (t + eself + SOFT_EPS);

    // phase C: accumulate; each lane owns channels [2*lane, 2*lane+1]
    float2 hv = *(const float2*)&h[(size_t)node * DD + lane * 2];
    float cself = eself * inv;
    float a0 = hv.x * cself, a1 = hv.y * cself;

    for (int c = 0; c < deg; c += 64) {
        int my = c + lane;
        int ms = (my < deg) ? srcs[r0 + my] : 0;
        float mc = (my < deg) ? __expf(lrelu(a_src[ms] + adst) - m) * inv : 0.f;
        int lim = min(64, deg - c);
        for (int jj = 0; jj < lim; ++jj) {
            float coef = __shfl(mc, jj);
            int s = __shfl(ms, jj);
            float2 hs = *(const float2*)&h[(size_t)s * DD + lane * 2];
            a0 += hs.x * coef;
            a1 += hs.y * coef;
        }
    }
    *(float2*)&out[(size_t)node * DD + lane * 2] = make_float2(a0, a1);
}

extern "C" void kernel_launch(void* const* d_in, const int* in_sizes, int n_in,
                              void* d_out, int out_size, void* d_ws, size_t ws_size,
                              hipStream_t stream) {
    const float* x       = (const float*)d_in[0];
    const int*   ei      = (const int*)d_in[1];
    const float* W       = (const float*)d_in[2];
    const float* att_src = (const float*)d_in[3];
    const float* att_dst = (const float*)d_in[4];
    float* out = (float*)d_out;

    const int N = in_sizes[0] / DD;     // 50000
    const int E = in_sizes[1] / 2;      // 1600000

    // workspace: h[N*128] | a_src[N] | a_dst[N] | off[N+1] | deg[N] | parts[256] | srcs[E]
    float* h      = (float*)d_ws;
    float* a_src  = h + (size_t)N * DD;
    float* a_dst  = a_src + N;
    int*   off    = (int*)(a_dst + N);
    int*   deg    = off + (N + 1);
    int*   parts  = deg + N;
    int*   srcs   = parts + 256;

    const int nparts = (N + 1023) / 1024;   // 49 for N=50000

    k_gemm<<<(N + 63) / 64, 256, 0, stream>>>(x, W, h, N);
    k_node_scores<<<(N * 64 + 255) / 256, 256, 0, stream>>>(h, att_src, att_dst,
                                                            a_src, a_dst, N);
    k_zero<<<(N + 255) / 256, 256, 0, stream>>>(deg, N);
    k_hist<<<(E + 255) / 256, 256, 0, stream>>>(ei, deg, E);
    k_scan1<<<nparts, 256, 0, stream>>>(deg, off, parts, N);
    k_scan2<<<1, 256, 0, stream>>>(parts, nparts);
    k_scan3<<<(N + 255) / 256, 256, 0, stream>>>(off, parts, deg, N, E);
    k_fill<<<(E + 255) / 256, 256, 0, stream>>>(ei, off, deg, srcs, E);
    k_agg<<<(N * 64 + 255) / 256, 256, 0, stream>>>(off, srcs, h, a_src, a_dst,
                                                    out, N);
}

// Round 3
// 398.628 us; speedup vs baseline: 7.4205x; 1.0652x over previous
//
#include <hip/hip_runtime.h>
#include <math.h>

#define DD 128
#define NEG_SLOPE 0.2f
#define SOFT_EPS 1e-16f

__device__ __forceinline__ float lrelu(float v) {
    return v >= 0.f ? v : NEG_SLOPE * v;
}

// ---- K1: h = x @ W  + fused per-node attention scores + deg zeroing ----
// block = 256; tile = 64 rows x 128 cols; per-thread 8 rows x 4 cols
__global__ __launch_bounds__(256) void k_gemm(
        const float* __restrict__ x, const float* __restrict__ W,
        const float* __restrict__ att_src, const float* __restrict__ att_dst,
        float* __restrict__ h, float* __restrict__ a_src,
        float* __restrict__ a_dst, int* __restrict__ deg, int N) {
    __shared__ float sX[64 * 32];
    __shared__ float sW[32 * DD];
    const int tid = threadIdx.x;
    const int cg = tid & 31;
    const int rg = tid >> 5;
    const int rbase = blockIdx.x * 64;

    // fold in deg zeroing (grid covers N: 782 blocks x 256 = 200k >= 50k)
    int gtid = blockIdx.x * 256 + tid;
    if (gtid < N) deg[gtid] = 0;

    float4 acc[8];
#pragma unroll
    for (int r = 0; r < 8; ++r) acc[r] = make_float4(0.f, 0.f, 0.f, 0.f);

    for (int kc = 0; kc < 4; ++kc) {
        const int kbase = kc * 32;
#pragma unroll
        for (int i = 0; i < 2; ++i) {
            int lin = tid + i * 256;
            int row = lin >> 3;
            int k4  = lin & 7;
            int grow = rbase + row;
            float4 v = make_float4(0.f, 0.f, 0.f, 0.f);
            if (grow < N) v = *(const float4*)&x[(size_t)grow * DD + kbase + k4 * 4];
            *(float4*)&sX[row * 32 + k4 * 4] = v;
        }
#pragma unroll
        for (int i = 0; i < 4; ++i) {
            int lin = tid + i * 256;
            int krow = lin >> 5;
            int c4 = lin & 31;
            *(float4*)&sW[krow * DD + c4 * 4] =
                *(const float4*)&W[(size_t)(kbase + krow) * DD + c4 * 4];
        }
        __syncthreads();
#pragma unroll
        for (int kk = 0; kk < 32; ++kk) {
            float4 w = *(float4*)&sW[kk * DD + cg * 4];
#pragma unroll
            for (int r = 0; r < 8; ++r) {
                float xv = sX[(rg * 8 + r) * 32 + kk];
                acc[r].x += xv * w.x; acc[r].y += xv * w.y;
                acc[r].z += xv * w.z; acc[r].w += xv * w.w;
            }
        }
        __syncthreads();
    }

    float4 as4 = *(const float4*)&att_src[cg * 4];
    float4 ad4 = *(const float4*)&att_dst[cg * 4];
#pragma unroll
    for (int r = 0; r < 8; ++r) {
        int grow = rbase + rg * 8 + r;
        if (grow < N) *(float4*)&h[(size_t)grow * DD + cg * 4] = acc[r];
        // fused node scores: reduce partial dots across the 32 lanes (cg)
        float ps = acc[r].x * as4.x + acc[r].y * as4.y +
                   acc[r].z * as4.z + acc[r].w * as4.w;
        float pd = acc[r].x * ad4.x + acc[r].y * ad4.y +
                   acc[r].z * ad4.z + acc[r].w * ad4.w;
#pragma unroll
        for (int o = 16; o; o >>= 1) {
            ps += __shfl_xor(ps, o);
            pd += __shfl_xor(pd, o);
        }
        if (cg == 0 && grow < N) { a_src[grow] = ps; a_dst[grow] = pd; }
    }
}

// ---- CSR build ----
__global__ __launch_bounds__(256) void k_hist(
        const int* __restrict__ ei, int* __restrict__ deg, int E) {
    int e = blockIdx.x * 256 + threadIdx.x;
    if (e >= E) return;
    atomicAdd(&deg[ei[E + e]], 1);
}

__global__ __launch_bounds__(256) void k_scan1(
        const int* __restrict__ deg, int* __restrict__ off,
        int* __restrict__ parts, int N) {
    __shared__ int sm[256];
    int t = threadIdx.x;
    int base = blockIdx.x * 1024 + t * 4;
    int v[4];
    int sum = 0;
#pragma unroll
    for (int i = 0; i < 4; ++i) {
        int idx = base + i;
        v[i] = (idx < N) ? deg[idx] : 0;
        sum += v[i];
    }
    sm[t] = sum;
    __syncthreads();
    for (int ofs = 1; ofs < 256; ofs <<= 1) {
        int xv = (t >= ofs) ? sm[t - ofs] : 0;
        __syncthreads();
        sm[t] += xv;
        __syncthreads();
    }
    int run = sm[t] - sum;
    if (t == 255) parts[blockIdx.x] = sm[255];
#pragma unroll
    for (int i = 0; i < 4; ++i) {
        int idx = base + i;
        if (idx < N) off[idx] = run;
        run += v[i];
    }
}

__global__ __launch_bounds__(256) void k_scan2(int* __restrict__ parts, int nparts) {
    __shared__ int sm[256];
    int t = threadIdx.x;
    int v = (t < nparts) ? parts[t] : 0;
    sm[t] = v;
    __syncthreads();
    for (int ofs = 1; ofs < 256; ofs <<= 1) {
        int xv = (t >= ofs) ? sm[t - ofs] : 0;
        __syncthreads();
        sm[t] += xv;
        __syncthreads();
    }
    if (t < nparts) parts[t] = sm[t] - v;
}

__global__ __launch_bounds__(256) void k_scan3(
        int* __restrict__ off, const int* __restrict__ parts,
        int* __restrict__ deg, int N, int E) {
    int i = blockIdx.x * 256 + threadIdx.x;
    if (i < N) {
        off[i] += parts[i >> 10];
        deg[i] = 0;
    }
    if (i == 0) off[N] = E;
}

__global__ __launch_bounds__(256) void k_fill(
        const int* __restrict__ ei, const int* __restrict__ off,
        int* __restrict__ cur, int* __restrict__ srcs, int E) {
    int e = blockIdx.x * 256 + threadIdx.x;
    if (e >= E) return;
    int s = ei[e], d = ei[E + e];
    int pos = off[d] + atomicAdd(&cur[d], 1);
    srcs[pos] = s;
}

// 8-wide unrolled gather-accumulate step (independent loads for MLP)
#define GATHER8(msv, mexv, JJ)                                                 \
    {                                                                          \
        int s0 = __shfl(msv, (JJ) + 0), s1 = __shfl(msv, (JJ) + 1);            \
        int s2 = __shfl(msv, (JJ) + 2), s3 = __shfl(msv, (JJ) + 3);            \
        int s4 = __shfl(msv, (JJ) + 4), s5 = __shfl(msv, (JJ) + 5);            \
        int s6 = __shfl(msv, (JJ) + 6), s7 = __shfl(msv, (JJ) + 7);            \
        float c0 = __shfl(mexv, (JJ) + 0), c1 = __shfl(mexv, (JJ) + 1);        \
        float c2 = __shfl(mexv, (JJ) + 2), c3 = __shfl(mexv, (JJ) + 3);        \
        float c4 = __shfl(mexv, (JJ) + 4), c5 = __shfl(mexv, (JJ) + 5);        \
        float c6 = __shfl(mexv, (JJ) + 6), c7 = __shfl(mexv, (JJ) + 7);        \
        float2 h0 = *(const float2*)&h[(size_t)s0 * DD + lane * 2];            \
        float2 h1 = *(const float2*)&h[(size_t)s1 * DD + lane * 2];            \
        float2 h2 = *(const float2*)&h[(size_t)s2 * DD + lane * 2];            \
        float2 h3 = *(const float2*)&h[(size_t)s3 * DD + lane * 2];            \
        float2 h4 = *(const float2*)&h[(size_t)s4 * DD + lane * 2];            \
        float2 h5 = *(const float2*)&h[(size_t)s5 * DD + lane * 2];            \
        float2 h6 = *(const float2*)&h[(size_t)s6 * DD + lane * 2];            \
        float2 h7 = *(const float2*)&h[(size_t)s7 * DD + lane * 2];            \
        a0 += h0.x * c0 + h1.x * c1 + h2.x * c2 + h3.x * c3 +                  \
              h4.x * c4 + h5.x * c5 + h6.x * c6 + h7.x * c7;                   \
        a1 += h0.y * c0 + h1.y * c1 + h2.y * c2 + h3.y * c3 +                  \
              h4.y * c4 + h5.y * c5 + h6.y * c6 + h7.y * c7;                   \
    }

// ---- K-agg: one wave per dst node; single-pass exp+accumulate ----
__global__ __launch_bounds__(256) void k_agg(
        const int* __restrict__ off, const int* __restrict__ srcs,
        const float* __restrict__ h,
        const float* __restrict__ a_src, const float* __restrict__ a_dst,
        float* __restrict__ out, int N) {
    int node = (blockIdx.x * 256 + threadIdx.x) >> 6;
    int lane = threadIdx.x & 63;
    if (node >= N) return;
    int r0 = off[node];
    int deg = off[node + 1] - r0;
    float adst = a_dst[node];
    float self_al = lrelu(a_src[node] + adst);
    float2 hv = *(const float2*)&h[(size_t)node * DD + lane * 2];
    float a0, a1, inv;

    if (deg <= 64) {
        // fast path: all edge data lives in one register per lane
        int ms = 0;
        float als = -1e30f;
        if (lane < deg) {
            ms = srcs[r0 + lane];
            als = lrelu(a_src[ms] + adst);
        }
        float m = fmaxf(self_al, als);
#pragma unroll
        for (int o = 32; o; o >>= 1) m = fmaxf(m, __shfl_xor(m, o));
        float mex = (lane < deg) ? __expf(als - m) : 0.f;
        float t = mex;
#pragma unroll
        for (int o = 32; o; o >>= 1) t += __shfl_xor(t, o);
        float eself = __expf(self_al - m);
        inv = 1.f / (t + eself + SOFT_EPS);
        a0 = hv.x * eself; a1 = hv.y * eself;
        int jj = 0;
        for (; jj + 8 <= deg; jj += 8) GATHER8(ms, mex, jj);
        for (; jj < deg; ++jj) {
            int s = __shfl(ms, jj);
            float cc = __shfl(mex, jj);
            float2 hs = *(const float2*)&h[(size_t)s * DD + lane * 2];
            a0 += hs.x * cc; a1 += hs.y * cc;
        }
    } else {
        // generic path: two passes (max, then exp+accumulate unscaled)
        float m = self_al;
        for (int j = lane; j < deg; j += 64) {
            int s = srcs[r0 + j];
            m = fmaxf(m, lrelu(a_src[s] + adst));
        }
#pragma unroll
        for (int o = 32; o; o >>= 1) m = fmaxf(m, __shfl_xor(m, o));
        float eself = __expf(self_al - m);
        a0 = hv.x * eself; a1 = hv.y * eself;
        float t = 0.f;
        for (int c = 0; c < deg; c += 64) {
            int my = c + lane;
            int ms = (my < deg) ? srcs[r0 + my] : 0;
            float mex = (my < deg) ? __expf(lrelu(a_src[ms] + adst) - m) : 0.f;
            t += mex;
            int lim = min(64, deg - c);
            int jj = 0;
            for (; jj + 8 <= lim; jj += 8) GATHER8(ms, mex, jj);
            for (; jj < lim; ++jj) {
                int s = __shfl(ms, jj);
                float cc = __shfl(mex, jj);
                float2 hs = *(const float2*)&h[(size_t)s * DD + lane * 2];
                a0 += hs.x * cc; a1 += hs.y * cc;
            }
        }
#pragma unroll
        for (int o = 32; o; o >>= 1) t += __shfl_xor(t, o);
        inv = 1.f / (t + eself + SOFT_EPS);
    }
    a0 *= inv; a1 *= inv;
    *(float2*)&out[(size_t)node * DD + lane * 2] = make_float2(a0, a1);
}

extern "C" void kernel_launch(void* const* d_in, const int* in_sizes, int n_in,
                              void* d_out, int out_size, void* d_ws, size_t ws_size,
                              hipStream_t stream) {
    const float* x       = (const float*)d_in[0];
    const int*   ei      = (const int*)d_in[1];
    const float* W       = (const float*)d_in[2];
    const float* att_src = (const float*)d_in[3];
    const float* att_dst = (const float*)d_in[4];
    float* out = (float*)d_out;

    const int N = in_sizes[0] / DD;     // 50000
    const int E = in_sizes[1] / 2;      // 1600000

    // workspace: h[N*128] | a_src[N] | a_dst[N] | off[N+1] | deg[N] | parts[256] | srcs[E]
    float* h      = (float*)d_ws;
    float* a_src  = h + (size_t)N * DD;
    float* a_dst  = a_src + N;
    int*   off    = (int*)(a_dst + N);
    int*   deg    = off + (N + 1);
    int*   parts  = deg + N;
    int*   srcs   = parts + 256;

    const int nparts = (N + 1023) / 1024;   // 49 for N=50000

    k_gemm<<<(N + 63) / 64, 256, 0, stream>>>(x, W, att_src, att_dst,
                                              h, a_src, a_dst, deg, N);
    k_hist<<<(E + 255) / 256, 256, 0, stream>>>(ei, deg, E);
    k_scan1<<<nparts, 256, 0, stream>>>(deg, off, parts, N);
    k_scan2<<<1, 256, 0, stream>>>(parts, nparts);
    k_scan3<<<(N + 255) / 256, 256, 0, stream>>>(off, parts, deg, N, E);
    k_fill<<<(E + 255) / 256, 256, 0, stream>>>(ei, off, deg, srcs, E);
    k_agg<<<(N * 64 + 255) / 256, 256, 0, stream>>>(off, srcs, h, a_src, a_dst,
                                                    out, N);
}

// Round 4
// 283.441 us; speedup vs baseline: 10.4361x; 1.4064x over previous
//
#include <hip/hip_runtime.h>
#include <math.h>

#define DD 128
#define NEG_SLOPE 0.2f
#define SOFT_EPS 1e-16f
#define CHUNK 4096   // edges per block in bucketing passes
// bucket b = dst >> 8 (256 nodes per bucket); requires N <= 65536 for packing

__device__ __forceinline__ float lrelu(float v) {
    return v >= 0.f ? v : NEG_SLOPE * v;
}

// ---- K1: h = x @ W  + fused per-node attention scores ----
__global__ __launch_bounds__(256) void k_gemm(
        const float* __restrict__ x, const float* __restrict__ W,
        const float* __restrict__ att_src, const float* __restrict__ att_dst,
        float* __restrict__ h, float* __restrict__ a_src,
        float* __restrict__ a_dst, int N) {
    __shared__ float sX[64 * 32];
    __shared__ float sW[32 * DD];
    const int tid = threadIdx.x;
    const int cg = tid & 31;
    const int rg = tid >> 5;
    const int rbase = blockIdx.x * 64;

    float4 acc[8];
#pragma unroll
    for (int r = 0; r < 8; ++r) acc[r] = make_float4(0.f, 0.f, 0.f, 0.f);

    for (int kc = 0; kc < 4; ++kc) {
        const int kbase = kc * 32;
#pragma unroll
        for (int i = 0; i < 2; ++i) {
            int lin = tid + i * 256;
            int row = lin >> 3;
            int k4  = lin & 7;
            int grow = rbase + row;
            float4 v = make_float4(0.f, 0.f, 0.f, 0.f);
            if (grow < N) v = *(const float4*)&x[(size_t)grow * DD + kbase + k4 * 4];
            *(float4*)&sX[row * 32 + k4 * 4] = v;
        }
#pragma unroll
        for (int i = 0; i < 4; ++i) {
            int lin = tid + i * 256;
            int krow = lin >> 5;
            int c4 = lin & 31;
            *(float4*)&sW[krow * DD + c4 * 4] =
                *(const float4*)&W[(size_t)(kbase + krow) * DD + c4 * 4];
        }
        __syncthreads();
#pragma unroll
        for (int kk = 0; kk < 32; ++kk) {
            float4 w = *(float4*)&sW[kk * DD + cg * 4];
#pragma unroll
            for (int r = 0; r < 8; ++r) {
                float xv = sX[(rg * 8 + r) * 32 + kk];
                acc[r].x += xv * w.x; acc[r].y += xv * w.y;
                acc[r].z += xv * w.z; acc[r].w += xv * w.w;
            }
        }
        __syncthreads();
    }

    float4 as4 = *(const float4*)&att_src[cg * 4];
    float4 ad4 = *(const float4*)&att_dst[cg * 4];
#pragma unroll
    for (int r = 0; r < 8; ++r) {
        int grow = rbase + rg * 8 + r;
        if (grow < N) *(float4*)&h[(size_t)grow * DD + cg * 4] = acc[r];
        float ps = acc[r].x * as4.x + acc[r].y * as4.y +
                   acc[r].z * as4.z + acc[r].w * as4.w;
        float pd = acc[r].x * ad4.x + acc[r].y * ad4.y +
                   acc[r].z * ad4.z + acc[r].w * ad4.w;
#pragma unroll
        for (int o = 16; o; o >>= 1) {
            ps += __shfl_xor(ps, o);
            pd += __shfl_xor(pd, o);
        }
        if (cg == 0 && grow < N) { a_src[grow] = ps; a_dst[grow] = pd; }
    }
}

// ---- coarse bucket histogram (LDS-staged) ----
__global__ __launch_bounds__(256) void k_bhist(
        const int* __restrict__ ei, int* __restrict__ bktCnt, int E, int NB) {
    __shared__ int sh[256];
    int t = threadIdx.x;
    sh[t] = 0;
    __syncthreads();
    int base = blockIdx.x * CHUNK;
    int lim = min(CHUNK, E - base);
    for (int i = t; i < lim; i += 256) {
        int d = ei[E + base + i];
        atomicAdd(&sh[d >> 8], 1);
    }
    __syncthreads();
    if (t < NB && sh[t]) atomicAdd(&bktCnt[t], sh[t]);
}

// ---- scan bucket sizes -> bases + cursors; also off[N]=E ----
__global__ __launch_bounds__(256) void k_bscan(
        const int* __restrict__ bktCnt, int* __restrict__ bktBase,
        int* __restrict__ bktCur, int* __restrict__ off,
        int NB, int N, int E) {
    __shared__ int sm[256];
    int t = threadIdx.x;
    int v = (t < NB) ? bktCnt[t] : 0;
    sm[t] = v;
    __syncthreads();
    for (int ofs = 1; ofs < 256; ofs <<= 1) {
        int xv = (t >= ofs) ? sm[t - ofs] : 0;
        __syncthreads();
        sm[t] += xv;
        __syncthreads();
    }
    int excl = sm[t] - v;
    if (t < NB) { bktBase[t] = excl; bktCur[t] = excl; }
    if (t == NB - 1) bktBase[NB] = excl + v;   // == E
    if (t == 0) off[N] = E;
}

// ---- coarse scatter into bucket regions (packed dlocal<<16 | src) ----
__global__ __launch_bounds__(256) void k_bucket(
        const int* __restrict__ ei, int* __restrict__ bktCur,
        int* __restrict__ pairs, int E, int NB) {
    __shared__ int cnt[256];
    __shared__ int gbase[256];
    int t = threadIdx.x;
    cnt[t] = 0;
    __syncthreads();
    int base = blockIdx.x * CHUNK;
    int lim = min(CHUNK, E - base);
    for (int i = t; i < lim; i += 256) {
        int d = ei[E + base + i];
        atomicAdd(&cnt[d >> 8], 1);
    }
    __syncthreads();
    if (t < NB && cnt[t]) gbase[t] = atomicAdd(&bktCur[t], cnt[t]);
    __syncthreads();
    cnt[t] = 0;
    __syncthreads();
    for (int i = t; i < lim; i += 256) {
        int s = ei[base + i];
        int d = ei[E + base + i];
        int b = d >> 8;
        int r = atomicAdd(&cnt[b], 1);
        pairs[gbase[b] + r] = s | ((d & 255) << 16);
    }
}

// ---- fine grouping: one block per bucket; builds off[] and sorted srcs[] ----
__global__ __launch_bounds__(256) void k_group(
        const int* __restrict__ bktBase, const int* __restrict__ pairs,
        int* __restrict__ off, int* __restrict__ srcs, int N) {
    __shared__ int cnt[256];
    __shared__ int excl[256];
    int b = blockIdx.x;
    int t = threadIdx.x;
    int r0 = bktBase[b], r1 = bktBase[b + 1];
    int ne = r1 - r0;
    cnt[t] = 0;
    __syncthreads();
    for (int i = t; i < ne; i += 256) {
        atomicAdd(&cnt[pairs[r0 + i] >> 16], 1);
    }
    __syncthreads();
    int v = cnt[t];
    excl[t] = v;
    __syncthreads();
    for (int ofs = 1; ofs < 256; ofs <<= 1) {
        int xv = (t >= ofs) ? excl[t - ofs] : 0;
        __syncthreads();
        excl[t] += xv;
        __syncthreads();
    }
    int my_excl = excl[t] - v;
    __syncthreads();
    excl[t] = my_excl;
    int node = b * 256 + t;
    if (node < N) off[node] = r0 + my_excl;
    cnt[t] = 0;
    __syncthreads();
    for (int i = t; i < ne; i += 256) {
        int p = pairs[r0 + i];
        int dl = p >> 16;
        int r = atomicAdd(&cnt[dl], 1);
        srcs[r0 + excl[dl] + r] = p & 0xFFFF;
    }
}

// 8-wide unrolled gather-accumulate step (independent loads for MLP)
#define GATHER8(msv, mexv, JJ)                                                 \
    {                                                                          \
        int s0 = __shfl(msv, (JJ) + 0), s1 = __shfl(msv, (JJ) + 1);            \
        int s2 = __shfl(msv, (JJ) + 2), s3 = __shfl(msv, (JJ) + 3);            \
        int s4 = __shfl(msv, (JJ) + 4), s5 = __shfl(msv, (JJ) + 5);            \
        int s6 = __shfl(msv, (JJ) + 6), s7 = __shfl(msv, (JJ) + 7);            \
        float c0 = __shfl(mexv, (JJ) + 0), c1 = __shfl(mexv, (JJ) + 1);        \
        float c2 = __shfl(mexv, (JJ) + 2), c3 = __shfl(mexv, (JJ) + 3);        \
        float c4 = __shfl(mexv, (JJ) + 4), c5 = __shfl(mexv, (JJ) + 5);        \
        float c6 = __shfl(mexv, (JJ) + 6), c7 = __shfl(mexv, (JJ) + 7);        \
        float2 h0 = *(const float2*)&h[(size_t)s0 * DD + lane * 2];            \
        float2 h1 = *(const float2*)&h[(size_t)s1 * DD + lane * 2];            \
        float2 h2 = *(const float2*)&h[(size_t)s2 * DD + lane * 2];            \
        float2 h3 = *(const float2*)&h[(size_t)s3 * DD + lane * 2];            \
        float2 h4 = *(const float2*)&h[(size_t)s4 * DD + lane * 2];            \
        float2 h5 = *(const float2*)&h[(size_t)s5 * DD + lane * 2];            \
        float2 h6 = *(const float2*)&h[(size_t)s6 * DD + lane * 2];            \
        float2 h7 = *(const float2*)&h[(size_t)s7 * DD + lane * 2];            \
        a0 += h0.x * c0 + h1.x * c1 + h2.x * c2 + h3.x * c3 +                  \
              h4.x * c4 + h5.x * c5 + h6.x * c6 + h7.x * c7;                   \
        a1 += h0.y * c0 + h1.y * c1 + h2.y * c2 + h3.y * c3 +                  \
              h4.y * c4 + h5.y * c5 + h6.y * c6 + h7.y * c7;                   \
    }

// ---- K-agg: one wave per dst node ----
__global__ __launch_bounds__(256) void k_agg(
        const int* __restrict__ off, const int* __restrict__ srcs,
        const float* __restrict__ h,
        const float* __restrict__ a_src, const float* __restrict__ a_dst,
        float* __restrict__ out, int N) {
    int node = (blockIdx.x * 256 + threadIdx.x) >> 6;
    int lane = threadIdx.x & 63;
    if (node >= N) return;
    int r0 = off[node];
    int deg = off[node + 1] - r0;
    float adst = a_dst[node];
    float self_al = lrelu(a_src[node] + adst);
    float2 hv = *(const float2*)&h[(size_t)node * DD + lane * 2];
    float a0, a1, inv;

    if (deg <= 64) {
        int ms = 0;
        float als = -1e30f;
        if (lane < deg) {
            ms = srcs[r0 + lane];
            als = lrelu(a_src[ms] + adst);
        }
        float m = fmaxf(self_al, als);
#pragma unroll
        for (int o = 32; o; o >>= 1) m = fmaxf(m, __shfl_xor(m, o));
        float mex = (lane < deg) ? __expf(als - m) : 0.f;
        float t = mex;
#pragma unroll
        for (int o = 32; o; o >>= 1) t += __shfl_xor(t, o);
        float eself = __expf(self_al - m);
        inv = 1.f / (t + eself + SOFT_EPS);
        a0 = hv.x * eself; a1 = hv.y * eself;
        int jj = 0;
        for (; jj + 8 <= deg; jj += 8) GATHER8(ms, mex, jj);
        for (; jj < deg; ++jj) {
            int s = __shfl(ms, jj);
            float cc = __shfl(mex, jj);
            float2 hs = *(const float2*)&h[(size_t)s * DD + lane * 2];
            a0 += hs.x * cc; a1 += hs.y * cc;
        }
    } else {
        float m = self_al;
        for (int j = lane; j < deg; j += 64) {
            int s = srcs[r0 + j];
            m = fmaxf(m, lrelu(a_src[s] + adst));
        }
#pragma unroll
        for (int o = 32; o; o >>= 1) m = fmaxf(m, __shfl_xor(m, o));
        float eself = __expf(self_al - m);
        a0 = hv.x * eself; a1 = hv.y * eself;
        float t = 0.f;
        for (int c = 0; c < deg; c += 64) {
            int my = c + lane;
            int ms = (my < deg) ? srcs[r0 + my] : 0;
            float mex = (my < deg) ? __expf(lrelu(a_src[ms] + adst) - m) : 0.f;
            t += mex;
            int lim = min(64, deg - c);
            int jj = 0;
            for (; jj + 8 <= lim; jj += 8) GATHER8(ms, mex, jj);
            for (; jj < lim; ++jj) {
                int s = __shfl(ms, jj);
                float cc = __shfl(mex, jj);
                float2 hs = *(const float2*)&h[(size_t)s * DD + lane * 2];
                a0 += hs.x * cc; a1 += hs.y * cc;
            }
        }
#pragma unroll
        for (int o = 32; o; o >>= 1) t += __shfl_xor(t, o);
        inv = 1.f / (t + eself + SOFT_EPS);
    }
    a0 *= inv; a1 *= inv;
    *(float2*)&out[(size_t)node * DD + lane * 2] = make_float2(a0, a1);
}

extern "C" void kernel_launch(void* const* d_in, const int* in_sizes, int n_in,
                              void* d_out, int out_size, void* d_ws, size_t ws_size,
                              hipStream_t stream) {
    const float* x       = (const float*)d_in[0];
    const int*   ei      = (const int*)d_in[1];
    const float* W       = (const float*)d_in[2];
    const float* att_src = (const float*)d_in[3];
    const float* att_dst = (const float*)d_in[4];
    float* out = (float*)d_out;

    const int N = in_sizes[0] / DD;     // 50000
    const int E = in_sizes[1] / 2;      // 1600000
    const int NB = (N + 255) >> 8;      // 196 coarse buckets

    // ws: h[N*128] | a_src[N] | a_dst[N] | off[N+1] | bktCnt[NB] | bktBase[NB+1]
    //     | bktCur[NB] | pairs[E] | srcs[E]   (~39 MB)
    float* h       = (float*)d_ws;
    float* a_src   = h + (size_t)N * DD;
    float* a_dst   = a_src + N;
    int*   off     = (int*)(a_dst + N);
    int*   bktCnt  = off + (N + 1);
    int*   bktBase = bktCnt + NB;
    int*   bktCur  = bktBase + NB + 1;
    int*   pairs   = bktCur + NB;
    int*   srcs    = pairs + E;

    const int eblocks = (E + CHUNK - 1) / CHUNK;

    hipMemsetAsync(bktCnt, 0, NB * sizeof(int), stream);
    k_gemm<<<(N + 63) / 64, 256, 0, stream>>>(x, W, att_src, att_dst,
                                              h, a_src, a_dst, N);
    k_bhist<<<eblocks, 256, 0, stream>>>(ei, bktCnt, E, NB);
    k_bscan<<<1, 256, 0, stream>>>(bktCnt, bktBase, bktCur, off, NB, N, E);
    k_bucket<<<eblocks, 256, 0, stream>>>(ei, bktCur, pairs, E, NB);
    k_group<<<NB, 256, 0, stream>>>(bktBase, pairs, off, srcs, N);
    k_agg<<<(N * 64 + 255) / 256, 256, 0, stream>>>(off, srcs, h, a_src, a_dst,
                                                    out, N);
}

// Round 5
// 228.629 us; speedup vs baseline: 12.9381x; 1.2397x over previous
//
#include <hip/hip_runtime.h>
#include <math.h>

#define DD 128
#define NEG_SLOPE 0.2f
#define SOFT_EPS 1e-16f
#define CHUNK 4096   // edges per block in bucketing passes
// bucket b = dst >> 8 (256 nodes per bucket); requires N <= 65536 (u16 srcs)

__device__ __forceinline__ float lrelu(float v) {
    return v >= 0.f ? v : NEG_SLOPE * v;
}
// bf16 pack/unpack (round-to-nearest-even)
__device__ __forceinline__ unsigned f2bf(float f) {
    unsigned u = __float_as_uint(f);
    return (u + 0x7FFFu + ((u >> 16) & 1u)) >> 16;
}
__device__ __forceinline__ float bfx(unsigned p) {   // low bf16
    return __uint_as_float(p << 16);
}
__device__ __forceinline__ float bfy(unsigned p) {   // high bf16
    return __uint_as_float(p & 0xFFFF0000u);
}

// ---- K1: h = x @ W (bf16 out) + fused node scores + fused coarse histogram
__global__ __launch_bounds__(256) void k_gemm(
        const float* __restrict__ x, const float* __restrict__ W,
        const float* __restrict__ att_src, const float* __restrict__ att_dst,
        unsigned* __restrict__ h32, float* __restrict__ a_src,
        float* __restrict__ a_dst,
        const int* __restrict__ ei, int* __restrict__ bktCnt,
        int N, int E, int NB, int eblocks) {
    __shared__ float sX[64 * 32];
    __shared__ float sW[32 * DD];
    __shared__ int sh[256];
    const int tid = threadIdx.x;
    const int cg = tid & 31;
    const int rg = tid >> 5;
    const int rbase = blockIdx.x * 64;

    // fused coarse bucket histogram (blocks 0..eblocks-1 each take a chunk)
    sh[tid] = 0;
    __syncthreads();
    if ((int)blockIdx.x < eblocks) {
        int base = blockIdx.x * CHUNK;
        int lim = min(CHUNK, E - base);
        for (int i = tid; i < lim; i += 256) {
            int d = ei[E + base + i];
            atomicAdd(&sh[d >> 8], 1);
        }
    }
    // (no sync needed here: first gemm __syncthreads orders sh before flush)

    float4 acc[8];
#pragma unroll
    for (int r = 0; r < 8; ++r) acc[r] = make_float4(0.f, 0.f, 0.f, 0.f);

    for (int kc = 0; kc < 4; ++kc) {
        const int kbase = kc * 32;
#pragma unroll
        for (int i = 0; i < 2; ++i) {
            int lin = tid + i * 256;
            int row = lin >> 3;
            int k4  = lin & 7;
            int grow = rbase + row;
            float4 v = make_float4(0.f, 0.f, 0.f, 0.f);
            if (grow < N) v = *(const float4*)&x[(size_t)grow * DD + kbase + k4 * 4];
            *(float4*)&sX[row * 32 + k4 * 4] = v;
        }
#pragma unroll
        for (int i = 0; i < 4; ++i) {
            int lin = tid + i * 256;
            int krow = lin >> 5;
            int c4 = lin & 31;
            *(float4*)&sW[krow * DD + c4 * 4] =
                *(const float4*)&W[(size_t)(kbase + krow) * DD + c4 * 4];
        }
        __syncthreads();
#pragma unroll
        for (int kk = 0; kk < 32; ++kk) {
            float4 w = *(float4*)&sW[kk * DD + cg * 4];
#pragma unroll
            for (int r = 0; r < 8; ++r) {
                float xv = sX[(rg * 8 + r) * 32 + kk];
                acc[r].x += xv * w.x; acc[r].y += xv * w.y;
                acc[r].z += xv * w.z; acc[r].w += xv * w.w;
            }
        }
        __syncthreads();
    }

    float4 as4 = *(const float4*)&att_src[cg * 4];
    float4 ad4 = *(const float4*)&att_dst[cg * 4];
#pragma unroll
    for (int r = 0; r < 8; ++r) {
        int grow = rbase + rg * 8 + r;
        if (grow < N) {
            uint2 p;
            p.x = f2bf(acc[r].x) | (f2bf(acc[r].y) << 16);
            p.y = f2bf(acc[r].z) | (f2bf(acc[r].w) << 16);
            *(uint2*)&h32[(size_t)grow * 64 + cg * 2] = p;
        }
        float ps = acc[r].x * as4.x + acc[r].y * as4.y +
                   acc[r].z * as4.z + acc[r].w * as4.w;
        float pd = acc[r].x * ad4.x + acc[r].y * ad4.y +
                   acc[r].z * ad4.z + acc[r].w * ad4.w;
#pragma unroll
        for (int o = 16; o; o >>= 1) {
            ps += __shfl_xor(ps, o);
            pd += __shfl_xor(pd, o);
        }
        if (cg == 0 && grow < N) { a_src[grow] = ps; a_dst[grow] = pd; }
    }
    // flush histogram (last __syncthreads in k-loop ordered all sh atomics)
    if (tid < NB) {
        int c = sh[tid];
        if (c) atomicAdd(&bktCnt[tid], c);
    }
}

// ---- scan bucket sizes -> bases + cursors; also off[N]=E ----
__global__ __launch_bounds__(256) void k_bscan(
        const int* __restrict__ bktCnt, int* __restrict__ bktBase,
        int* __restrict__ bktCur, int* __restrict__ off,
        int NB, int N, int E) {
    __shared__ int sm[256];
    int t = threadIdx.x;
    int v = (t < NB) ? bktCnt[t] : 0;
    sm[t] = v;
    __syncthreads();
    for (int ofs = 1; ofs < 256; ofs <<= 1) {
        int xv = (t >= ofs) ? sm[t - ofs] : 0;
        __syncthreads();
        sm[t] += xv;
        __syncthreads();
    }
    int excl = sm[t] - v;
    if (t < NB) { bktBase[t] = excl; bktCur[t] = excl; }
    if (t == NB - 1) bktBase[NB] = excl + v;   // == E
    if (t == 0) off[N] = E;
}

// ---- coarse scatter into bucket regions (packed dlocal<<16 | src) ----
__global__ __launch_bounds__(256) void k_bucket(
        const int* __restrict__ ei, int* __restrict__ bktCur,
        int* __restrict__ pairs, int E, int NB) {
    __shared__ int cnt[256];
    __shared__ int gbase[256];
    int t = threadIdx.x;
    cnt[t] = 0;
    __syncthreads();
    int base = blockIdx.x * CHUNK;
    int lim = min(CHUNK, E - base);
    for (int i = t; i < lim; i += 256) {
        int d = ei[E + base + i];
        atomicAdd(&cnt[d >> 8], 1);
    }
    __syncthreads();
    if (t < NB && cnt[t]) gbase[t] = atomicAdd(&bktCur[t], cnt[t]);
    __syncthreads();
    cnt[t] = 0;
    __syncthreads();
    for (int i = t; i < lim; i += 256) {
        int s = ei[base + i];
        int d = ei[E + base + i];
        int b = d >> 8;
        int r = atomicAdd(&cnt[b], 1);
        pairs[gbase[b] + r] = s | ((d & 255) << 16);
    }
}

// ---- fine grouping: one block per bucket; builds off[] and u16 srcs[] ----
__global__ __launch_bounds__(256) void k_group(
        const int* __restrict__ bktBase, const int* __restrict__ pairs,
        int* __restrict__ off, unsigned short* __restrict__ srcs, int N) {
    __shared__ int cnt[256];
    __shared__ int excl[256];
    int b = blockIdx.x;
    int t = threadIdx.x;
    int r0 = bktBase[b], r1 = bktBase[b + 1];
    int ne = r1 - r0;
    cnt[t] = 0;
    __syncthreads();
    for (int i = t; i < ne; i += 256) {
        atomicAdd(&cnt[pairs[r0 + i] >> 16], 1);
    }
    __syncthreads();
    int v = cnt[t];
    excl[t] = v;
    __syncthreads();
    for (int ofs = 1; ofs < 256; ofs <<= 1) {
        int xv = (t >= ofs) ? excl[t - ofs] : 0;
        __syncthreads();
        excl[t] += xv;
        __syncthreads();
    }
    int my_excl = excl[t] - v;
    __syncthreads();
    excl[t] = my_excl;
    int node = b * 256 + t;
    if (node < N) off[node] = r0 + my_excl;
    cnt[t] = 0;
    __syncthreads();
    for (int i = t; i < ne; i += 256) {
        int p = pairs[r0 + i];
        int dl = p >> 16;
        int r = atomicAdd(&cnt[dl], 1);
        srcs[r0 + excl[dl] + r] = (unsigned short)(p & 0xFFFF);
    }
}

// 8-wide unrolled gather-accumulate (bf16x2 loads, fp32 accumulate)
#define GATHER8(msv, mexv, JJ)                                                 \
    {                                                                          \
        int s0 = __shfl(msv, (JJ) + 0), s1 = __shfl(msv, (JJ) + 1);            \
        int s2 = __shfl(msv, (JJ) + 2), s3 = __shfl(msv, (JJ) + 3);            \
        int s4 = __shfl(msv, (JJ) + 4), s5 = __shfl(msv, (JJ) + 5);            \
        int s6 = __shfl(msv, (JJ) + 6), s7 = __shfl(msv, (JJ) + 7);            \
        float c0 = __shfl(mexv, (JJ) + 0), c1 = __shfl(mexv, (JJ) + 1);        \
        float c2 = __shfl(mexv, (JJ) + 2), c3 = __shfl(mexv, (JJ) + 3);        \
        float c4 = __shfl(mexv, (JJ) + 4), c5 = __shfl(mexv, (JJ) + 5);        \
        float c6 = __shfl(mexv, (JJ) + 6), c7 = __shfl(mexv, (JJ) + 7);        \
        unsigned u0 = h32[(size_t)s0 * 64 + lane];                             \
        unsigned u1 = h32[(size_t)s1 * 64 + lane];                             \
        unsigned u2 = h32[(size_t)s2 * 64 + lane];                             \
        unsigned u3 = h32[(size_t)s3 * 64 + lane];                             \
        unsigned u4 = h32[(size_t)s4 * 64 + lane];                             \
        unsigned u5 = h32[(size_t)s5 * 64 + lane];                             \
        unsigned u6 = h32[(size_t)s6 * 64 + lane];                             \
        unsigned u7 = h32[(size_t)s7 * 64 + lane];                             \
        a0 += bfx(u0) * c0 + bfx(u1) * c1 + bfx(u2) * c2 + bfx(u3) * c3 +      \
              bfx(u4) * c4 + bfx(u5) * c5 + bfx(u6) * c6 + bfx(u7) * c7;       \
        a1 += bfy(u0) * c0 + bfy(u1) * c1 + bfy(u2) * c2 + bfy(u3) * c3 +      \
              bfy(u4) * c4 + bfy(u5) * c5 + bfy(u6) * c6 + bfy(u7) * c7;       \
    }

// ---- K-agg: one wave per dst node ----
__global__ __launch_bounds__(256) void k_agg(
        const int* __restrict__ off, const unsigned short* __restrict__ srcs,
        const unsigned* __restrict__ h32,
        const float* __restrict__ a_src, const float* __restrict__ a_dst,
        float* __restrict__ out, int N) {
    int node = (blockIdx.x * 256 + threadIdx.x) >> 6;
    int lane = threadIdx.x & 63;
    if (node >= N) return;
    int r0 = off[node];
    int deg = off[node + 1] - r0;
    float adst = a_dst[node];
    float self_al = lrelu(a_src[node] + adst);
    unsigned uself = h32[(size_t)node * 64 + lane];
    float a0, a1, inv;

    if (deg <= 64) {
        int ms = 0;
        float als = -1e30f;
        if (lane < deg) {
            ms = srcs[r0 + lane];
            als = lrelu(a_src[ms] + adst);
        }
        float m = fmaxf(self_al, als);
#pragma unroll
        for (int o = 32; o; o >>= 1) m = fmaxf(m, __shfl_xor(m, o));
        float mex = (lane < deg) ? __expf(als - m) : 0.f;
        float t = mex;
#pragma unroll
        for (int o = 32; o; o >>= 1) t += __shfl_xor(t, o);
        float eself = __expf(self_al - m);
        inv = 1.f / (t + eself + SOFT_EPS);
        a0 = bfx(uself) * eself; a1 = bfy(uself) * eself;
        int jj = 0;
        for (; jj + 8 <= deg; jj += 8) GATHER8(ms, mex, jj);
        for (; jj < deg; ++jj) {
            int s = __shfl(ms, jj);
            float cc = __shfl(mex, jj);
            unsigned u = h32[(size_t)s * 64 + lane];
            a0 += bfx(u) * cc; a1 += bfy(u) * cc;
        }
    } else {
        float m = self_al;
        for (int j = lane; j < deg; j += 64) {
            int s = srcs[r0 + j];
            m = fmaxf(m, lrelu(a_src[s] + adst));
        }
#pragma unroll
        for (int o = 32; o; o >>= 1) m = fmaxf(m, __shfl_xor(m, o));
        float eself = __expf(self_al - m);
        a0 = bfx(uself) * eself; a1 = bfy(uself) * eself;
        float t = 0.f;
        for (int c = 0; c < deg; c += 64) {
            int my = c + lane;
            int ms = (my < deg) ? (int)srcs[r0 + my] : 0;
            float mex = (my < deg) ? __expf(lrelu(a_src[ms] + adst) - m) : 0.f;
            t += mex;
            int lim = min(64, deg - c);
            int jj = 0;
            for (; jj + 8 <= lim; jj += 8) GATHER8(ms, mex, jj);
            for (; jj < lim; ++jj) {
                int s = __shfl(ms, jj);
                float cc = __shfl(mex, jj);
                unsigned u = h32[(size_t)s * 64 + lane];
                a0 += bfx(u) * cc; a1 += bfy(u) * cc;
            }
        }
#pragma unroll
        for (int o = 32; o; o >>= 1) t += __shfl_xor(t, o);
        inv = 1.f / (t + eself + SOFT_EPS);
    }
    a0 *= inv; a1 *= inv;
    *(float2*)&out[(size_t)node * DD + lane * 2] = make_float2(a0, a1);
}

extern "C" void kernel_launch(void* const* d_in, const int* in_sizes, int n_in,
                              void* d_out, int out_size, void* d_ws, size_t ws_size,
                              hipStream_t stream) {
    const float* x       = (const float*)d_in[0];
    const int*   ei      = (const int*)d_in[1];
    const float* W       = (const float*)d_in[2];
    const float* att_src = (const float*)d_in[3];
    const float* att_dst = (const float*)d_in[4];
    float* out = (float*)d_out;

    const int N = in_sizes[0] / DD;     // 50000
    const int E = in_sizes[1] / 2;      // 1600000
    const int NB = (N + 255) >> 8;      // 196 coarse buckets

    // ws: h32[N*64 u32 (bf16 h)] | a_src[N] | a_dst[N] | off[N+1] | bktCnt[NB]
    //     | bktBase[NB+1] | bktCur[NB] | pairs[E i32] | srcs[E u16]
    unsigned* h32     = (unsigned*)d_ws;
    float*    a_src   = (float*)(h32 + (size_t)N * 64);
    float*    a_dst   = a_src + N;
    int*      off     = (int*)(a_dst + N);
    int*      bktCnt  = off + (N + 1);
    int*      bktBase = bktCnt + NB;
    int*      bktCur  = bktBase + NB + 1;
    int*      pairs   = bktCur + NB;
    unsigned short* srcs = (unsigned short*)(pairs + E);

    const int eblocks = (E + CHUNK - 1) / CHUNK;

    hipMemsetAsync(bktCnt, 0, NB * sizeof(int), stream);
    k_gemm<<<(N + 63) / 64, 256, 0, stream>>>(x, W, att_src, att_dst,
                                              h32, a_src, a_dst,
                                              ei, bktCnt, N, E, NB, eblocks);
    k_bscan<<<1, 256, 0, stream>>>(bktCnt, bktBase, bktCur, off, NB, N, E);
    k_bucket<<<eblocks, 256, 0, stream>>>(ei, bktCur, pairs, E, NB);
    k_group<<<NB, 256, 0, stream>>>(bktBase, pairs, off, srcs, N);
    k_agg<<<(N * 64 + 255) / 256, 256, 0, stream>>>(off, srcs, h32, a_src,
                                                    a_dst, out, N);
}

// Round 6
// 215.440 us; speedup vs baseline: 13.7302x; 1.0612x over previous
//
#include <hip/hip_runtime.h>
#include <math.h>

#define DD 128
#define NEG_SLOPE 0.2f
#define SOFT_EPS 1e-16f
#define CHUNK 4096   // edges per block in bucketing passes
// bucket b = dst >> 8 (256 nodes per bucket); requires N <= 65536 (u16 srcs)

typedef __attribute__((ext_vector_type(8))) short short8;
typedef __attribute__((ext_vector_type(4))) float float4v;

__device__ __forceinline__ float lrelu(float v) {
    return v >= 0.f ? v : NEG_SLOPE * v;
}
// bf16 pack/unpack (round-to-nearest-even)
__device__ __forceinline__ unsigned f2bf(float f) {
    unsigned u = __float_as_uint(f);
    return (u + 0x7FFFu + ((u >> 16) & 1u)) >> 16;
}
__device__ __forceinline__ float bfx(unsigned p) {   // low bf16
    return __uint_as_float(p << 16);
}
__device__ __forceinline__ float bfy(unsigned p) {   // high bf16
    return __uint_as_float(p & 0xFFFF0000u);
}

// ---- K0: W[k][n] fp32 -> Wt bf16, layout Wt_u32[n*64 + i] packing k=2i,2i+1
__global__ __launch_bounds__(256) void k_wt(
        const float* __restrict__ W, unsigned* __restrict__ Wt) {
    int idx = blockIdx.x * 256 + threadIdx.x;   // 8192 outputs
    if (idx >= 128 * 64) return;
    int i = idx >> 7;          // k-pair index 0..63
    int n = idx & 127;         // coalesced reads across n
    float a = W[(2 * i) * 128 + n];
    float b = W[(2 * i + 1) * 128 + n];
    Wt[n * 64 + i] = f2bf(a) | (f2bf(b) << 16);
}

// ---- K1: h = x @ W via MFMA bf16 (no LDS staging) + node scores + histogram
// block = 256 (4 waves); wave w computes rows [rbase+w*16, +16) x all 128 cols
__global__ __launch_bounds__(256) void k_gemm(
        const float* __restrict__ x, const unsigned* __restrict__ Wt,
        const float* __restrict__ att_src, const float* __restrict__ att_dst,
        unsigned* __restrict__ h32, float* __restrict__ a_src,
        float* __restrict__ a_dst,
        const int* __restrict__ ei, int* __restrict__ bktCnt,
        int N, int E, int NB, int eblocks) {
    __shared__ int sh[256];
    const int tid = threadIdx.x;
    const int w = tid >> 6;
    const int l = tid & 63;
    const int m = l & 15;          // A-row within wave tile / C col (n)
    const int quad = l >> 4;       // k-chunk selector within fragment
    const int rbase = blockIdx.x * 64;

    // fused coarse bucket histogram
    sh[tid] = 0;
    __syncthreads();
    if ((int)blockIdx.x < eblocks) {
        int base = blockIdx.x * CHUNK;
        int lim = min(CHUNK, E - base);
        for (int i = tid; i < lim; i += 256) {
            int d = ei[E + base + i];
            atomicAdd(&sh[d >> 8], 1);
        }
    }

    // A fragments: row = rbase + w*16 + m, k = c*32 + quad*8 + j
    int arow = rbase + w * 16 + m;
    bool av = arow < N;
    const float* xr = &x[(size_t)arow * DD];
    short8 af[4];
#pragma unroll
    for (int c = 0; c < 4; ++c) {
        int k0 = c * 32 + quad * 8;
        float4 p0 = make_float4(0.f, 0.f, 0.f, 0.f);
        float4 p1 = make_float4(0.f, 0.f, 0.f, 0.f);
        if (av) {
            p0 = *(const float4*)&xr[k0];
            p1 = *(const float4*)&xr[k0 + 4];
        }
        uint4 u;
        u.x = f2bf(p0.x) | (f2bf(p0.y) << 16);
        u.y = f2bf(p0.z) | (f2bf(p0.w) << 16);
        u.z = f2bf(p1.x) | (f2bf(p1.y) << 16);
        u.w = f2bf(p1.z) | (f2bf(p1.w) << 16);
        af[c] = __builtin_bit_cast(short8, u);
    }

    const int n = m;               // C/D col index
    float ps[4] = {0.f, 0.f, 0.f, 0.f};
    float pd[4] = {0.f, 0.f, 0.f, 0.f};

#pragma unroll
    for (int ct = 0; ct < 8; ++ct) {
        // B fragments straight from Wt: B[k=c*32+quad*8+j][ct*16+n]
        short8 bf[4];
#pragma unroll
        for (int c = 0; c < 4; ++c) {
            uint4 bu = *(const uint4*)&Wt[(size_t)(ct * 16 + n) * 64 +
                                          c * 16 + quad * 4];
            bf[c] = __builtin_bit_cast(short8, bu);
        }
        float4v acc = {0.f, 0.f, 0.f, 0.f};
#pragma unroll
        for (int c = 0; c < 4; ++c)
            acc = __builtin_amdgcn_mfma_f32_16x16x32_bf16(af[c], bf[c], acc,
                                                          0, 0, 0);
        float asv = att_src[ct * 16 + n];
        float adv = att_dst[ct * 16 + n];
#pragma unroll
        for (int reg = 0; reg < 4; ++reg) {
            float v = acc[reg];
            ps[reg] += v * asv;
            pd[reg] += v * adv;
            float pr = __shfl_xor(v, 1);          // partner channel n^1
            if (!(l & 1)) {
                int rowo = rbase + w * 16 + quad * 4 + reg;
                if (rowo < N)
                    h32[(size_t)rowo * 64 + ((ct * 16 + n) >> 1)] =
                        f2bf(v) | (f2bf(pr) << 16);
            }
        }
    }
    // reduce node-score partials over the 16 n-lanes of each quad
#pragma unroll
    for (int reg = 0; reg < 4; ++reg) {
#pragma unroll
        for (int o = 1; o < 16; o <<= 1) {
            ps[reg] += __shfl_xor(ps[reg], o);
            pd[reg] += __shfl_xor(pd[reg], o);
        }
    }
    if ((l & 15) == 0) {
#pragma unroll
        for (int reg = 0; reg < 4; ++reg) {
            int rowo = rbase + w * 16 + quad * 4 + reg;
            if (rowo < N) { a_src[rowo] = ps[reg]; a_dst[rowo] = pd[reg]; }
        }
    }
    // flush histogram
    __syncthreads();
    if (tid < NB) {
        int c = sh[tid];
        if (c) atomicAdd(&bktCnt[tid], c);
    }
}

// ---- scan bucket sizes -> bases + cursors; also off[N]=E ----
__global__ __launch_bounds__(256) void k_bscan(
        const int* __restrict__ bktCnt, int* __restrict__ bktBase,
        int* __restrict__ bktCur, int* __restrict__ off,
        int NB, int N, int E) {
    __shared__ int sm[256];
    int t = threadIdx.x;
    int v = (t < NB) ? bktCnt[t] : 0;
    sm[t] = v;
    __syncthreads();
    for (int ofs = 1; ofs < 256; ofs <<= 1) {
        int xv = (t >= ofs) ? sm[t - ofs] : 0;
        __syncthreads();
        sm[t] += xv;
        __syncthreads();
    }
    int excl = sm[t] - v;
    if (t < NB) { bktBase[t] = excl; bktCur[t] = excl; }
    if (t == NB - 1) bktBase[NB] = excl + v;   // == E
    if (t == 0) off[N] = E;
}

// ---- coarse scatter into bucket regions (packed dlocal<<16 | src) ----
__global__ __launch_bounds__(256) void k_bucket(
        const int* __restrict__ ei, int* __restrict__ bktCur,
        int* __restrict__ pairs, int E, int NB) {
    __shared__ int cnt[256];
    __shared__ int gbase[256];
    int t = threadIdx.x;
    cnt[t] = 0;
    __syncthreads();
    int base = blockIdx.x * CHUNK;
    int lim = min(CHUNK, E - base);
    for (int i = t; i < lim; i += 256) {
        int d = ei[E + base + i];
        atomicAdd(&cnt[d >> 8], 1);
    }
    __syncthreads();
    if (t < NB && cnt[t]) gbase[t] = atomicAdd(&bktCur[t], cnt[t]);
    __syncthreads();
    cnt[t] = 0;
    __syncthreads();
    for (int i = t; i < lim; i += 256) {
        int s = ei[base + i];
        int d = ei[E + base + i];
        int b = d >> 8;
        int r = atomicAdd(&cnt[b], 1);
        pairs[gbase[b] + r] = s | ((d & 255) << 16);
    }
}

// ---- fine grouping: one block per bucket; builds off[] and u16 srcs[] ----
__global__ __launch_bounds__(256) void k_group(
        const int* __restrict__ bktBase, const int* __restrict__ pairs,
        int* __restrict__ off, unsigned short* __restrict__ srcs, int N) {
    __shared__ int cnt[256];
    __shared__ int excl[256];
    int b = blockIdx.x;
    int t = threadIdx.x;
    int r0 = bktBase[b], r1 = bktBase[b + 1];
    int ne = r1 - r0;
    cnt[t] = 0;
    __syncthreads();
    for (int i = t; i < ne; i += 256) {
        atomicAdd(&cnt[pairs[r0 + i] >> 16], 1);
    }
    __syncthreads();
    int v = cnt[t];
    excl[t] = v;
    __syncthreads();
    for (int ofs = 1; ofs < 256; ofs <<= 1) {
        int xv = (t >= ofs) ? excl[t - ofs] : 0;
        __syncthreads();
        excl[t] += xv;
        __syncthreads();
    }
    int my_excl = excl[t] - v;
    __syncthreads();
    excl[t] = my_excl;
    int node = b * 256 + t;
    if (node < N) off[node] = r0 + my_excl;
    cnt[t] = 0;
    __syncthreads();
    for (int i = t; i < ne; i += 256) {
        int p = pairs[r0 + i];
        int dl = p >> 16;
        int r = atomicAdd(&cnt[dl], 1);
        srcs[r0 + excl[dl] + r] = (unsigned short)(p & 0xFFFF);
    }
}

// 8-wide unrolled gather-accumulate (bf16x2 loads, fp32 accumulate)
#define GATHER8(msv, mexv, JJ)                                                 \
    {                                                                          \
        int s0 = __shfl(msv, (JJ) + 0), s1 = __shfl(msv, (JJ) + 1);            \
        int s2 = __shfl(msv, (JJ) + 2), s3 = __shfl(msv, (JJ) + 3);            \
        int s4 = __shfl(msv, (JJ) + 4), s5 = __shfl(msv, (JJ) + 5);            \
        int s6 = __shfl(msv, (JJ) + 6), s7 = __shfl(msv, (JJ) + 7);            \
        float c0 = __shfl(mexv, (JJ) + 0), c1 = __shfl(mexv, (JJ) + 1);        \
        float c2 = __shfl(mexv, (JJ) + 2), c3 = __shfl(mexv, (JJ) + 3);        \
        float c4 = __shfl(mexv, (JJ) + 4), c5 = __shfl(mexv, (JJ) + 5);        \
        float c6 = __shfl(mexv, (JJ) + 6), c7 = __shfl(mexv, (JJ) + 7);        \
        unsigned u0 = h32[(size_t)s0 * 64 + lane];                             \
        unsigned u1 = h32[(size_t)s1 * 64 + lane];                             \
        unsigned u2 = h32[(size_t)s2 * 64 + lane];                             \
        unsigned u3 = h32[(size_t)s3 * 64 + lane];                             \
        unsigned u4 = h32[(size_t)s4 * 64 + lane];                             \
        unsigned u5 = h32[(size_t)s5 * 64 + lane];                             \
        unsigned u6 = h32[(size_t)s6 * 64 + lane];                             \
        unsigned u7 = h32[(size_t)s7 * 64 + lane];                             \
        a0 += bfx(u0) * c0 + bfx(u1) * c1 + bfx(u2) * c2 + bfx(u3) * c3 +      \
              bfx(u4) * c4 + bfx(u5) * c5 + bfx(u6) * c6 + bfx(u7) * c7;       \
        a1 += bfy(u0) * c0 + bfy(u1) * c1 + bfy(u2) * c2 + bfy(u3) * c3 +      \
              bfy(u4) * c4 + bfy(u5) * c5 + bfy(u6) * c6 + bfy(u7) * c7;       \
    }

// ---- K-agg: one wave per dst node ----
__global__ __launch_bounds__(256) void k_agg(
        const int* __restrict__ off, const unsigned short* __restrict__ srcs,
        const unsigned* __restrict__ h32,
        const float* __restrict__ a_src, const float* __restrict__ a_dst,
        float* __restrict__ out, int N) {
    int node = (blockIdx.x * 256 + threadIdx.x) >> 6;
    int lane = threadIdx.x & 63;
    if (node >= N) return;
    int r0 = off[node];
    int deg = off[node + 1] - r0;
    float adst = a_dst[node];
    float self_al = lrelu(a_src[node] + adst);
    unsigned uself = h32[(size_t)node * 64 + lane];
    float a0, a1, inv;

    if (deg <= 64) {
        int ms = 0;
        float als = -1e30f;
        if (lane < deg) {
            ms = srcs[r0 + lane];
            als = lrelu(a_src[ms] + adst);
        }
        float m = fmaxf(self_al, als);
#pragma unroll
        for (int o = 32; o; o >>= 1) m = fmaxf(m, __shfl_xor(m, o));
        float mex = (lane < deg) ? __expf(als - m) : 0.f;
        float t = mex;
#pragma unroll
        for (int o = 32; o; o >>= 1) t += __shfl_xor(t, o);
        float eself = __expf(self_al - m);
        inv = 1.f / (t + eself + SOFT_EPS);
        a0 = bfx(uself) * eself; a1 = bfy(uself) * eself;
        int jj = 0;
        for (; jj + 8 <= deg; jj += 8) GATHER8(ms, mex, jj);
        for (; jj < deg; ++jj) {
            int s = __shfl(ms, jj);
            float cc = __shfl(mex, jj);
            unsigned u = h32[(size_t)s * 64 + lane];
            a0 += bfx(u) * cc; a1 += bfy(u) * cc;
        }
    } else {
        float m = self_al;
        for (int j = lane; j < deg; j += 64) {
            int s = srcs[r0 + j];
            m = fmaxf(m, lrelu(a_src[s] + adst));
        }
#pragma unroll
        for (int o = 32; o; o >>= 1) m = fmaxf(m, __shfl_xor(m, o));
        float eself = __expf(self_al - m);
        a0 = bfx(uself) * eself; a1 = bfy(uself) * eself;
        float t = 0.f;
        for (int c = 0; c < deg; c += 64) {
            int my = c + lane;
            int ms = (my < deg) ? (int)srcs[r0 + my] : 0;
            float mex = (my < deg) ? __expf(lrelu(a_src[ms] + adst) - m) : 0.f;
            t += mex;
            int lim = min(64, deg - c);
            int jj = 0;
            for (; jj + 8 <= lim; jj += 8) GATHER8(ms, mex, jj);
            for (; jj < lim; ++jj) {
                int s = __shfl(ms, jj);
                float cc = __shfl(mex, jj);
                unsigned u = h32[(size_t)s * 64 + lane];
                a0 += bfx(u) * cc; a1 += bfy(u) * cc;
            }
        }
#pragma unroll
        for (int o = 32; o; o >>= 1) t += __shfl_xor(t, o);
        inv = 1.f / (t + eself + SOFT_EPS);
    }
    a0 *= inv; a1 *= inv;
    *(float2*)&out[(size_t)node * DD + lane * 2] = make_float2(a0, a1);
}

extern "C" void kernel_launch(void* const* d_in, const int* in_sizes, int n_in,
                              void* d_out, int out_size, void* d_ws, size_t ws_size,
                              hipStream_t stream) {
    const float* x       = (const float*)d_in[0];
    const int*   ei      = (const int*)d_in[1];
    const float* W       = (const float*)d_in[2];
    const float* att_src = (const float*)d_in[3];
    const float* att_dst = (const float*)d_in[4];
    float* out = (float*)d_out;

    const int N = in_sizes[0] / DD;     // 50000
    const int E = in_sizes[1] / 2;      // 1600000
    const int NB = (N + 255) >> 8;      // 196 coarse buckets

    // ws: h32[N*64] | a_src[N] | a_dst[N] | off[N+1] | bktCnt[NB]
    //     | bktBase[NB+1] | bktCur[NB] | Wt[8192] | pairs[E i32] | srcs[E u16]
    unsigned* h32     = (unsigned*)d_ws;
    float*    a_src   = (float*)(h32 + (size_t)N * 64);
    float*    a_dst   = a_src + N;
    int*      off     = (int*)(a_dst + N);
    int*      bktCnt  = off + (N + 1);
    int*      bktBase = bktCnt + NB;
    int*      bktCur  = bktBase + NB + 1;
    unsigned* Wt      = (unsigned*)(bktCur + NB);
    int*      pairs   = (int*)(Wt + 8192);
    unsigned short* srcs = (unsigned short*)(pairs + E);

    const int eblocks = (E + CHUNK - 1) / CHUNK;

    hipMemsetAsync(bktCnt, 0, NB * sizeof(int), stream);
    k_wt<<<32, 256, 0, stream>>>(W, Wt);
    k_gemm<<<(N + 63) / 64, 256, 0, stream>>>(x, Wt, att_src, att_dst,
                                              h32, a_src, a_dst,
                                              ei, bktCnt, N, E, NB, eblocks);
    k_bscan<<<1, 256, 0, stream>>>(bktCnt, bktBase, bktCur, off, NB, N, E);
    k_bucket<<<eblocks, 256, 0, stream>>>(ei, bktCur, pairs, E, NB);
    k_group<<<NB, 256, 0, stream>>>(bktBase, pairs, off, srcs, N);
    k_agg<<<(N * 64 + 255) / 256, 256, 0, stream>>>(off, srcs, h32, a_src,
                                                    a_dst, out, N);
}

// Round 7
// 204.900 us; speedup vs baseline: 14.4364x; 1.0514x over previous
//
#include <hip/hip_runtime.h>
#include <math.h>

#define DD 128
#define NEG_SLOPE 0.2f
#define SOFT_EPS 1e-16f
#define CHUNK 4096    // edges per block in bucketing/histogram passes
#define RCAP 9216     // per-bucket rank-stash capacity (bucket ~8163 +- 90)
// bucket b = dst >> 8 (256 nodes); requires N <= 65536 (u16 srcs)

typedef __attribute__((ext_vector_type(8))) short short8;
typedef __attribute__((ext_vector_type(4))) float float4v;

__device__ __forceinline__ float lrelu(float v) {
    return v >= 0.f ? v : NEG_SLOPE * v;
}
__device__ __forceinline__ unsigned f2bf(float f) {
    unsigned u = __float_as_uint(f);
    return (u + 0x7FFFu + ((u >> 16) & 1u)) >> 16;
}
__device__ __forceinline__ unsigned pk(float a, float b) {
    return f2bf(a) | (f2bf(b) << 16);
}
__device__ __forceinline__ float bfx(unsigned p) {
    return __uint_as_float(p << 16);
}
__device__ __forceinline__ float bfy(unsigned p) {
    return __uint_as_float(p & 0xFFFF0000u);
}

// ---- K0: W[k][n] fp32 -> Wtf bf16 in MFMA B-fragment order ----
// Wtf4[(ct*4+c)*64 + l]: lane l (quad=l>>4, n=l&15) holds
// B[k = c*32+quad*8+j][col = ct*16+n], j=0..7, k-pairs packed low-first.
__global__ __launch_bounds__(256) void k_wt(
        const float* __restrict__ W, uint4* __restrict__ Wtf4) {
    int idx = blockIdx.x * 256 + threadIdx.x;    // 2048 entries
    if (idx >= 2048) return;
    int g = idx >> 6, l = idx & 63;
    int ct = g >> 2, c = g & 3;
    int quad = l >> 4, n = l & 15;
    int col = ct * 16 + n;
    int k0 = c * 32 + quad * 8;
    uint4 o;
    o.x = pk(W[(k0 + 0) * DD + col], W[(k0 + 1) * DD + col]);
    o.y = pk(W[(k0 + 2) * DD + col], W[(k0 + 3) * DD + col]);
    o.z = pk(W[(k0 + 4) * DD + col], W[(k0 + 5) * DD + col]);
    o.w = pk(W[(k0 + 6) * DD + col], W[(k0 + 7) * DD + col]);
    Wtf4[idx] = o;
}

// ---- K0b: x fp32 -> xf bf16 in MFMA A-fragment order (LDS-staged) ----
// xf4[t*256 + c*64 + l]: lane l (quad, m=l&15) holds
// A[row=16t+m][k=c*32+quad*8+j], j=0..7. Block stages 4 tiles (64 rows).
__global__ __launch_bounds__(256) void k_xf(
        const float* __restrict__ x, uint4* __restrict__ xf4,
        int N, int ntiles) {
    __shared__ float sx[64 * 132];
    const int t = threadIdx.x;
#pragma unroll
    for (int it = 0; it < 8; ++it) {
        int lin = it * 256 + t;          // float4 index, 2048 total
        int row = lin >> 5, c4 = lin & 31;
        int grow = blockIdx.x * 64 + row;
        float4 v = make_float4(0.f, 0.f, 0.f, 0.f);
        if (grow < N) v = *(const float4*)&x[(size_t)grow * DD + c4 * 4];
        *(float4*)&sx[row * 132 + c4 * 4] = v;
    }
    __syncthreads();
#pragma unroll
    for (int it = 0; it < 4; ++it) {
        int e = it * 256 + t;            // entry within block, 1024 total
        int tl = e >> 8;
        int tg = blockIdx.x * 4 + tl;
        if (tg >= ntiles) continue;
        int rem = e & 255;
        int l = rem & 63;
        int quad = l >> 4, m = l & 15;
        int c = rem >> 6;
        const float* p = &sx[(tl * 16 + m) * 132 + c * 32 + quad * 8];
        float4 v0 = *(const float4*)p;
        float4 v1 = *(const float4*)(p + 4);
        uint4 o;
        o.x = pk(v0.x, v0.y); o.y = pk(v0.z, v0.w);
        o.z = pk(v1.x, v1.y); o.w = pk(v1.z, v1.w);
        xf4[(size_t)tg * 256 + rem] = o;
    }
}

// ---- K1: h = xf @ Wtf via MFMA + node scores + fused coarse histogram ----
// block 256 = 4 waves; wave w owns tile t = blockIdx*4+w (16 rows x 128 cols)
__global__ __launch_bounds__(256) void k_gemm(
        const uint4* __restrict__ xf4, const uint4* __restrict__ Wtf4,
        const float* __restrict__ att_src, const float* __restrict__ att_dst,
        unsigned* __restrict__ h32, float* __restrict__ a_src,
        float* __restrict__ a_dst,
        const int* __restrict__ ei, int* __restrict__ bktCnt,
        int N, int E, int NB, int eblocks, int ntiles) {
    __shared__ int sh[256];
    __shared__ float sc[4 * 16 * 132];   // per-wave 16x132 fp32 C tile
    const int tid = threadIdx.x;
    const int w = tid >> 6;
    const int l = tid & 63;
    const int quad = l >> 4, n = l & 15;
    const int t = blockIdx.x * 4 + w;
    const bool tv = t < ntiles;

    // fused coarse bucket histogram
    sh[tid] = 0;
    __syncthreads();
    if ((int)blockIdx.x < eblocks) {
        int base = blockIdx.x * CHUNK;
        int lim = min(CHUNK, E - base);
        const int* dsts = ei + E + base;
        int nv4 = lim >> 2;
        for (int i4 = tid; i4 < nv4; i4 += 256) {
            int4 d4 = *(const int4*)&dsts[i4 * 4];
            atomicAdd(&sh[d4.x >> 8], 1); atomicAdd(&sh[d4.y >> 8], 1);
            atomicAdd(&sh[d4.z >> 8], 1); atomicAdd(&sh[d4.w >> 8], 1);
        }
        for (int i = nv4 * 4 + tid; i < lim; i += 256)
            atomicAdd(&sh[dsts[i] >> 8], 1);
    }

    float ps[4] = {0.f, 0.f, 0.f, 0.f};
    float pd[4] = {0.f, 0.f, 0.f, 0.f};
    if (tv) {
        short8 af[4];
#pragma unroll
        for (int c = 0; c < 4; ++c)
            af[c] = __builtin_bit_cast(short8, xf4[(size_t)t * 256 + c * 64 + l]);
#pragma unroll
        for (int ct = 0; ct < 8; ++ct) {
            float4v acc = {0.f, 0.f, 0.f, 0.f};
#pragma unroll
            for (int c = 0; c < 4; ++c) {
                short8 bfr = __builtin_bit_cast(short8, Wtf4[(ct * 4 + c) * 64 + l]);
                acc = __builtin_amdgcn_mfma_f32_16x16x32_bf16(af[c], bfr, acc,
                                                              0, 0, 0);
            }
            float asv = att_src[ct * 16 + n];
            float adv = att_dst[ct * 16 + n];
#pragma unroll
            for (int reg = 0; reg < 4; ++reg) {
                float v = acc[reg];
                ps[reg] += v * asv;
                pd[reg] += v * adv;
                sc[w * 2112 + (quad * 4 + reg) * 132 + ct * 16 + n] = v;
            }
        }
        // node scores: reduce over the 16 n-lanes
#pragma unroll
        for (int reg = 0; reg < 4; ++reg) {
#pragma unroll
            for (int o = 1; o < 16; o <<= 1) {
                ps[reg] += __shfl_xor(ps[reg], o);
                pd[reg] += __shfl_xor(pd[reg], o);
            }
        }
        if (n == 0) {
#pragma unroll
            for (int reg = 0; reg < 4; ++reg) {
                int grow = t * 16 + quad * 4 + reg;
                if (grow < N) { a_src[grow] = ps[reg]; a_dst[grow] = pd[reg]; }
            }
        }
    }
    __syncthreads();
    if (tv) {
        // coalesced bf16 store: each lane packs 8 fp32 -> uint4; 4 stores of
        // 1 KB contiguous per wave
#pragma unroll
        for (int s = 0; s < 4; ++s) {
            int row = s * 4 + quad;
            const float* p = &sc[w * 2112 + row * 132 + n * 8];
            float4 v0 = *(const float4*)p;
            float4 v1 = *(const float4*)(p + 4);
            uint4 o;
            o.x = pk(v0.x, v0.y); o.y = pk(v0.z, v0.w);
            o.z = pk(v1.x, v1.y); o.w = pk(v1.z, v1.w);
            int grow = t * 16 + row;
            if (grow < N) *(uint4*)&h32[(size_t)grow * 64 + n * 4] = o;
        }
    }
    // flush histogram
    if (tid < NB) {
        int c = sh[tid];
        if (c) atomicAdd(&bktCnt[tid], c);
    }
}

// ---- K2: coarse scatter into 4-aligned bucket regions; in-block scan ----
__global__ __launch_bounds__(256) void k_bucket(
        const int* __restrict__ ei, const int* __restrict__ bktCnt,
        int* __restrict__ bktCur, int* __restrict__ bktBase,
        int* __restrict__ pairs, int E, int NB) {
    __shared__ int cnt[256];
    __shared__ int gbase[256];
    __shared__ int sm[256];
    int t = threadIdx.x;
    cnt[t] = 0;
    __syncthreads();
    int base = blockIdx.x * CHUNK;
    int lim = min(CHUNK, E - base);
    const int* dsts = ei + E + base;
    const int* srcp = ei + base;
    int nv4 = lim >> 2;
    for (int i4 = t; i4 < nv4; i4 += 256) {
        int4 d4 = *(const int4*)&dsts[i4 * 4];
        atomicAdd(&cnt[d4.x >> 8], 1); atomicAdd(&cnt[d4.y >> 8], 1);
        atomicAdd(&cnt[d4.z >> 8], 1); atomicAdd(&cnt[d4.w >> 8], 1);
    }
    for (int i = nv4 * 4 + t; i < lim; i += 256)
        atomicAdd(&cnt[dsts[i] >> 8], 1);
    // exclusive scan of 4-padded global bucket counts -> aligned bases
    int bc = (t < NB) ? bktCnt[t] : 0;
    int pc = (bc + 3) & ~3;
    sm[t] = pc;
    __syncthreads();
    for (int ofs = 1; ofs < 256; ofs <<= 1) {
        int xv = (t >= ofs) ? sm[t - ofs] : 0;
        __syncthreads();
        sm[t] += xv;
        __syncthreads();
    }
    int sbase = sm[t] - pc;
    if (blockIdx.x == 0 && t < NB) bktBase[t] = sbase;
    int c = cnt[t];
    if (t < NB && c) gbase[t] = sbase + atomicAdd(&bktCur[t], c);
    __syncthreads();
    cnt[t] = 0;
    __syncthreads();
    for (int i4 = t; i4 < nv4; i4 += 256) {
        int4 s4 = *(const int4*)&srcp[i4 * 4];
        int4 d4 = *(const int4*)&dsts[i4 * 4];
        int b, r;
        b = d4.x >> 8; r = atomicAdd(&cnt[b], 1);
        pairs[gbase[b] + r] = s4.x | ((d4.x & 255) << 16);
        b = d4.y >> 8; r = atomicAdd(&cnt[b], 1);
        pairs[gbase[b] + r] = s4.y | ((d4.y & 255) << 16);
        b = d4.z >> 8; r = atomicAdd(&cnt[b], 1);
        pairs[gbase[b] + r] = s4.z | ((d4.z & 255) << 16);
        b = d4.w >> 8; r = atomicAdd(&cnt[b], 1);
        pairs[gbase[b] + r] = s4.w | ((d4.w & 255) << 16);
    }
    for (int i = nv4 * 4 + t; i < lim; i += 256) {
        int s = srcp[i], d = dsts[i];
        int b = d >> 8;
        int r = atomicAdd(&cnt[b], 1);
        pairs[gbase[b] + r] = s | ((d & 255) << 16);
    }
}

// ---- K3: fine grouping (1024 thr/bucket); rank-stash kills phase-3 atomics
__global__ __launch_bounds__(1024) void k_group(
        const int* __restrict__ bktBase, const int* __restrict__ bktCnt,
        const int* __restrict__ pairs, int* __restrict__ off,
        unsigned short* __restrict__ degw, unsigned short* __restrict__ srcs,
        int N) {
    __shared__ int cnt[256];
    __shared__ int excl[256];
    __shared__ unsigned short rnk[RCAP];
    int b = blockIdx.x, t = threadIdx.x;
    int r0 = bktBase[b];
    int ne = bktCnt[b];
    if (t < 256) cnt[t] = 0;
    __syncthreads();
    int nv4 = ne >> 2;
    bool fits = (ne <= RCAP);
    if (fits) {
        for (int i4 = t; i4 < nv4; i4 += 1024) {
            int4 p4 = *(const int4*)&pairs[r0 + i4 * 4];
            rnk[i4 * 4 + 0] = (unsigned short)atomicAdd(&cnt[p4.x >> 16], 1);
            rnk[i4 * 4 + 1] = (unsigned short)atomicAdd(&cnt[p4.y >> 16], 1);
            rnk[i4 * 4 + 2] = (unsigned short)atomicAdd(&cnt[p4.z >> 16], 1);
            rnk[i4 * 4 + 3] = (unsigned short)atomicAdd(&cnt[p4.w >> 16], 1);
        }
        for (int i = nv4 * 4 + t; i < ne; i += 1024)
            rnk[i] = (unsigned short)atomicAdd(&cnt[pairs[r0 + i] >> 16], 1);
    } else {
        for (int i = t; i < ne; i += 1024)
            atomicAdd(&cnt[pairs[r0 + i] >> 16], 1);
    }
    __syncthreads();
    int v = 0;
    if (t < 256) { v = cnt[t]; excl[t] = v; }
    __syncthreads();
    for (int ofs = 1; ofs < 256; ofs <<= 1) {
        int xv = 0;
        if (t < 256 && t >= ofs) xv = excl[t - ofs];
        __syncthreads();
        if (t < 256) excl[t] += xv;
        __syncthreads();
    }
    if (t < 256) {
        int me = excl[t] - v;
        excl[t] = me;
        int node = b * 256 + t;
        if (node < N) {
            off[node] = r0 + me;
            degw[node] = (unsigned short)v;
        }
    }
    __syncthreads();
    if (fits) {
        for (int i4 = t; i4 < nv4; i4 += 1024) {
            int4 p4 = *(const int4*)&pairs[r0 + i4 * 4];
            srcs[r0 + excl[p4.x >> 16] + rnk[i4 * 4 + 0]] = (unsigned short)(p4.x & 0xFFFF);
            srcs[r0 + excl[p4.y >> 16] + rnk[i4 * 4 + 1]] = (unsigned short)(p4.y & 0xFFFF);
            srcs[r0 + excl[p4.z >> 16] + rnk[i4 * 4 + 2]] = (unsigned short)(p4.z & 0xFFFF);
            srcs[r0 + excl[p4.w >> 16] + rnk[i4 * 4 + 3]] = (unsigned short)(p4.w & 0xFFFF);
        }
        for (int i = nv4 * 4 + t; i < ne; i += 1024) {
            int p = pairs[r0 + i];
            srcs[r0 + excl[p >> 16] + rnk[i]] = (unsigned short)(p & 0xFFFF);
        }
    } else {
        if (t < 256) cnt[t] = 0;
        __syncthreads();
        for (int i = t; i < ne; i += 1024) {
            int p = pairs[r0 + i];
            int dl = p >> 16;
            int r = atomicAdd(&cnt[dl], 1);
            srcs[r0 + excl[dl] + r] = (unsigned short)(p & 0xFFFF);
        }
    }
}

// 8-wide unrolled gather-accumulate (bf16x2 loads, fp32 accumulate)
#define GATHER8(msv, mexv, JJ)                                                 \
    {                                                                          \
        int s0 = __shfl(msv, (JJ) + 0), s1 = __shfl(msv, (JJ) + 1);            \
        int s2 = __shfl(msv, (JJ) + 2), s3 = __shfl(msv, (JJ) + 3);            \
        int s4 = __shfl(msv, (JJ) + 4), s5 = __shfl(msv, (JJ) + 5);            \
        int s6 = __shfl(msv, (JJ) + 6), s7 = __shfl(msv, (JJ) + 7);            \
        float c0 = __shfl(mexv, (JJ) + 0), c1 = __shfl(mexv, (JJ) + 1);        \
        float c2 = __shfl(mexv, (JJ) + 2), c3 = __shfl(mexv, (JJ) + 3);        \
        float c4 = __shfl(mexv, (JJ) + 4), c5 = __shfl(mexv, (JJ) + 5);        \
        float c6 = __shfl(mexv, (JJ) + 6), c7 = __shfl(mexv, (JJ) + 7);        \
        unsigned u0 = h32[(size_t)s0 * 64 + lane];                             \
        unsigned u1 = h32[(size_t)s1 * 64 + lane];                             \
        unsigned u2 = h32[(size_t)s2 * 64 + lane];                             \
        unsigned u3 = h32[(size_t)s3 * 64 + lane];                             \
        unsigned u4 = h32[(size_t)s4 * 64 + lane];                             \
        unsigned u5 = h32[(size_t)s5 * 64 + lane];                             \
        unsigned u6 = h32[(size_t)s6 * 64 + lane];                             \
        unsigned u7 = h32[(size_t)s7 * 64 + lane];                             \
        a0 += bfx(u0) * c0 + bfx(u1) * c1 + bfx(u2) * c2 + bfx(u3) * c3 +      \
              bfx(u4) * c4 + bfx(u5) * c5 + bfx(u6) * c6 + bfx(u7) * c7;       \
        a1 += bfy(u0) * c0 + bfy(u1) * c1 + bfy(u2) * c2 + bfy(u3) * c3 +      \
              bfy(u4) * c4 + bfy(u5) * c5 + bfy(u6) * c6 + bfy(u7) * c7;       \
    }

// ---- K4: one wave per dst node ----
__global__ __launch_bounds__(256) void k_agg(
        const int* __restrict__ off, const unsigned short* __restrict__ degw,
        const unsigned short* __restrict__ srcs,
        const unsigned* __restrict__ h32,
        const float* __restrict__ a_src, const float* __restrict__ a_dst,
        float* __restrict__ out, int N) {
    int node = (blockIdx.x * 256 + threadIdx.x) >> 6;
    int lane = threadIdx.x & 63;
    if (node >= N) return;
    int r0 = off[node];
    int deg = degw[node];
    float adst = a_dst[node];
    float self_al = lrelu(a_src[node] + adst);
    unsigned uself = h32[(size_t)node * 64 + lane];
    float a0, a1, inv;

    if (deg <= 64) {
        int ms = 0;
        float als = -1e30f;
        if (lane < deg) {
            ms = srcs[r0 + lane];
            als = lrelu(a_src[ms] + adst);
        }
        float m = fmaxf(self_al, als);
#pragma unroll
        for (int o = 32; o; o >>= 1) m = fmaxf(m, __shfl_xor(m, o));
        float mex = (lane < deg) ? __expf(als - m) : 0.f;
        float t = mex;
#pragma unroll
        for (int o = 32; o; o >>= 1) t += __shfl_xor(t, o);
        float eself = __expf(self_al - m);
        inv = 1.f / (t + eself + SOFT_EPS);
        a0 = bfx(uself) * eself; a1 = bfy(uself) * eself;
        int jj = 0;
        for (; jj + 8 <= deg; jj += 8) GATHER8(ms, mex, jj);
        for (; jj < deg; ++jj) {
            int s = __shfl(ms, jj);
            float cc = __shfl(mex, jj);
            unsigned u = h32[(size_t)s * 64 + lane];
            a0 += bfx(u) * cc; a1 += bfy(u) * cc;
        }
    } else {
        float m = self_al;
        for (int j = lane; j < deg; j += 64) {
            int s = srcs[r0 + j];
            m = fmaxf(m, lrelu(a_src[s] + adst));
        }
#pragma unroll
        for (int o = 32; o; o >>= 1) m = fmaxf(m, __shfl_xor(m, o));
        float eself = __expf(self_al - m);
        a0 = bfx(uself) * eself; a1 = bfy(uself) * eself;
        float t = 0.f;
        for (int c = 0; c < deg; c += 64) {
            int my = c + lane;
            int ms = (my < deg) ? (int)srcs[r0 + my] : 0;
            float mex = (my < deg) ? __expf(lrelu(a_src[ms] + adst) - m) : 0.f;
            t += mex;
            int lim = min(64, deg - c);
            int jj = 0;
            for (; jj + 8 <= lim; jj += 8) GATHER8(ms, mex, jj);
            for (; jj < lim; ++jj) {
                int s = __shfl(ms, jj);
                float cc = __shfl(mex, jj);
                unsigned u = h32[(size_t)s * 64 + lane];
                a0 += bfx(u) * cc; a1 += bfy(u) * cc;
            }
        }
#pragma unroll
        for (int o = 32; o; o >>= 1) t += __shfl_xor(t, o);
        inv = 1.f / (t + eself + SOFT_EPS);
    }
    a0 *= inv; a1 *= inv;
    *(float2*)&out[(size_t)node * DD + lane * 2] = make_float2(a0, a1);
}

extern "C" void kernel_launch(void* const* d_in, const int* in_sizes, int n_in,
                              void* d_out, int out_size, void* d_ws, size_t ws_size,
                              hipStream_t stream) {
    const float* x       = (const float*)d_in[0];
    const int*   ei      = (const int*)d_in[1];
    const float* W       = (const float*)d_in[2];
    const float* att_src = (const float*)d_in[3];
    const float* att_dst = (const float*)d_in[4];
    float* out = (float*)d_out;

    const int N = in_sizes[0] / DD;      // 50000
    const int E = in_sizes[1] / 2;       // 1600000
    const int NB = (N + 255) >> 8;       // 196
    const int ntiles = (N + 15) >> 4;    // 3125

    // ws (u32 units): h32[N*64] | a_src[N] | a_dst[N] | off[N] | degw[N u16]
    //   | bktCnt[NB] | bktCur[NB] | bktBase[256] | Wtf[8192] | xf[ntiles*1024]
    //   | pairs[E+1024] | srcs[E u16]
    unsigned* h32     = (unsigned*)d_ws;
    float*    a_src   = (float*)(h32 + (size_t)N * 64);
    float*    a_dst   = a_src + N;
    int*      off     = (int*)(a_dst + N);
    unsigned short* degw = (unsigned short*)(off + N);
    int*      bktCnt  = (int*)(degw + ((N + 1) & ~1));
    int*      bktCur  = bktCnt + NB;
    int*      bktBase = bktCur + NB;
    uint4*    Wtf4    = (uint4*)(bktBase + 256);
    uint4*    xf4     = Wtf4 + 2048;
    int*      pairs   = (int*)(xf4 + (size_t)ntiles * 256);
    unsigned short* srcs = (unsigned short*)(pairs + E + 1024);

    const int eblocks = (E + CHUNK - 1) / CHUNK;    // 391
    const int gblocks = (ntiles + 3) / 4;           // 782 >= eblocks

    hipMemsetAsync(bktCnt, 0, 2 * NB * sizeof(int), stream);
    k_wt<<<8, 256, 0, stream>>>(W, Wtf4);
    k_xf<<<gblocks, 256, 0, stream>>>(x, xf4, N, ntiles);
    k_gemm<<<gblocks, 256, 0, stream>>>(xf4, Wtf4, att_src, att_dst,
                                        h32, a_src, a_dst,
                                        ei, bktCnt, N, E, NB, eblocks, ntiles);
    k_bucket<<<eblocks, 256, 0, stream>>>(ei, bktCnt, bktCur, bktBase,
                                          pairs, E, NB);
    k_group<<<NB, 1024, 0, stream>>>(bktBase, bktCnt, pairs, off, degw,
                                     srcs, N);
    k_agg<<<(N * 64 + 255) / 256, 256, 0, stream>>>(off, degw, srcs, h32,
                                                    a_src, a_dst, out, N);
}

// Round 8
// 192.719 us; speedup vs baseline: 15.3489x; 1.0632x over previous
//
#include <hip/hip_runtime.h>
#include <math.h>

#define DD 128
#define NEG_SLOPE 0.2f
#define SOFT_EPS 1e-16f
#define CHUNK 4096    // edges per block in bucketing/histogram passes
#define RCAP 9216     // per-bucket rank-stash capacity (bucket ~8163 +- 90)
// bucket b = dst >> 8 (256 nodes); requires N <= 65536 (u16 srcs)

typedef __attribute__((ext_vector_type(8))) short short8;
typedef __attribute__((ext_vector_type(4))) float float4v;

__device__ __forceinline__ float lrelu(float v) {
    return v >= 0.f ? v : NEG_SLOPE * v;
}
__device__ __forceinline__ unsigned f2bf(float f) {
    unsigned u = __float_as_uint(f);
    return (u + 0x7FFFu + ((u >> 16) & 1u)) >> 16;
}
__device__ __forceinline__ unsigned pk(float a, float b) {
    return f2bf(a) | (f2bf(b) << 16);
}
__device__ __forceinline__ float bfx(unsigned p) {
    return __uint_as_float(p << 16);
}
__device__ __forceinline__ float bfy(unsigned p) {
    return __uint_as_float(p & 0xFFFF0000u);
}

// ---- K0: W -> Wtf (MFMA B-fragment order) + zero bktCnt/bktCur ----
// Wtf4[(ct*4+c)*64 + l]: lane l (quad=l>>4, n=l&15) holds
// B[k = c*32+quad*8+j][col = ct*16+n], j=0..7.
__global__ __launch_bounds__(256) void k_wt(
        const float* __restrict__ W, uint4* __restrict__ Wtf4,
        int* __restrict__ bktZero, int nz) {
    int idx = blockIdx.x * 256 + threadIdx.x;    // 2048 threads
    if (idx < nz) bktZero[idx] = 0;              // bktCnt | bktCur
    if (idx >= 2048) return;
    int g = idx >> 6, l = idx & 63;
    int ct = g >> 2, c = g & 3;
    int quad = l >> 4, n = l & 15;
    int col = ct * 16 + n;
    int k0 = c * 32 + quad * 8;
    uint4 o;
    o.x = pk(W[(k0 + 0) * DD + col], W[(k0 + 1) * DD + col]);
    o.y = pk(W[(k0 + 2) * DD + col], W[(k0 + 3) * DD + col]);
    o.z = pk(W[(k0 + 4) * DD + col], W[(k0 + 5) * DD + col]);
    o.w = pk(W[(k0 + 6) * DD + col], W[(k0 + 7) * DD + col]);
    Wtf4[idx] = o;
}

// ---- K1: h = x @ W via MFMA (x staged in LDS, fragments in-register),
//          fused node scores + fused coarse histogram ----
// block 256 = 4 waves; wave w owns tile t = blockIdx*4+w (16 rows x 128 cols)
// LDS: sx (64x132 fp32) is reused as the C-transpose scratch (disjoint phases)
__global__ __launch_bounds__(256) void k_gemm(
        const float* __restrict__ x, const uint4* __restrict__ Wtf4,
        const float* __restrict__ att_src, const float* __restrict__ att_dst,
        unsigned* __restrict__ h32, float* __restrict__ a_src,
        float* __restrict__ a_dst,
        const int* __restrict__ ei, int* __restrict__ bktCnt,
        int N, int E, int NB, int eblocks, int ntiles) {
    __shared__ int sh[256];
    __shared__ float sx[64 * 132];   // 33.8 KB: x-stage, then C-tile scratch
    const int tid = threadIdx.x;
    const int w = tid >> 6;
    const int l = tid & 63;
    const int quad = l >> 4, n = l & 15;   // n doubles as A-row m and C col
    const int t = blockIdx.x * 4 + w;
    const bool tv = t < ntiles;

    // fused coarse bucket histogram
    sh[tid] = 0;
    __syncthreads();
    if ((int)blockIdx.x < eblocks) {
        int base = blockIdx.x * CHUNK;
        int lim = min(CHUNK, E - base);
        const int* dsts = ei + E + base;
        int nv4 = lim >> 2;
        for (int i4 = tid; i4 < nv4; i4 += 256) {
            int4 d4 = *(const int4*)&dsts[i4 * 4];
            atomicAdd(&sh[d4.x >> 8], 1); atomicAdd(&sh[d4.y >> 8], 1);
            atomicAdd(&sh[d4.z >> 8], 1); atomicAdd(&sh[d4.w >> 8], 1);
        }
        for (int i = nv4 * 4 + tid; i < lim; i += 256)
            atomicAdd(&sh[dsts[i] >> 8], 1);
    }

    // stage 64 rows of x (fp32, coalesced float4)
#pragma unroll
    for (int it = 0; it < 8; ++it) {
        int lin = it * 256 + tid;        // float4 index, 2048 total
        int row = lin >> 5, c4 = lin & 31;
        int grow = blockIdx.x * 64 + row;
        float4 v = make_float4(0.f, 0.f, 0.f, 0.f);
        if (grow < N) v = *(const float4*)&x[(size_t)grow * DD + c4 * 4];
        *(float4*)&sx[row * 132 + c4 * 4] = v;
    }
    __syncthreads();

    // build A fragments in registers from LDS
    short8 af[4];
    if (tv) {
#pragma unroll
        for (int c = 0; c < 4; ++c) {
            const float* p = &sx[(w * 16 + n) * 132 + c * 32 + quad * 8];
            float4 v0 = *(const float4*)p;
            float4 v1 = *(const float4*)(p + 4);
            uint4 u;
            u.x = pk(v0.x, v0.y); u.y = pk(v0.z, v0.w);
            u.z = pk(v1.x, v1.y); u.w = pk(v1.z, v1.w);
            af[c] = __builtin_bit_cast(short8, u);
        }
    }
    __syncthreads();                      // sx now reusable as C scratch

    float ps[4] = {0.f, 0.f, 0.f, 0.f};
    float pd[4] = {0.f, 0.f, 0.f, 0.f};
    if (tv) {
#pragma unroll
        for (int ct = 0; ct < 8; ++ct) {
            float4v acc = {0.f, 0.f, 0.f, 0.f};
#pragma unroll
            for (int c = 0; c < 4; ++c) {
                short8 bfr = __builtin_bit_cast(short8,
                                                Wtf4[(ct * 4 + c) * 64 + l]);
                acc = __builtin_amdgcn_mfma_f32_16x16x32_bf16(af[c], bfr, acc,
                                                              0, 0, 0);
            }
            float asv = att_src[ct * 16 + n];
            float adv = att_dst[ct * 16 + n];
#pragma unroll
            for (int reg = 0; reg < 4; ++reg) {
                float v = acc[reg];
                ps[reg] += v * asv;
                pd[reg] += v * adv;
                sx[w * 2112 + (quad * 4 + reg) * 132 + ct * 16 + n] = v;
            }
        }
        // node scores: reduce over the 16 n-lanes
#pragma unroll
        for (int reg = 0; reg < 4; ++reg) {
#pragma unroll
            for (int o = 1; o < 16; o <<= 1) {
                ps[reg] += __shfl_xor(ps[reg], o);
                pd[reg] += __shfl_xor(pd[reg], o);
            }
        }
        if (n == 0) {
#pragma unroll
            for (int reg = 0; reg < 4; ++reg) {
                int grow = t * 16 + quad * 4 + reg;
                if (grow < N) { a_src[grow] = ps[reg]; a_dst[grow] = pd[reg]; }
            }
        }
    }
    __syncthreads();
    if (tv) {
        // coalesced bf16 store: 4 x 1 KB contiguous per wave
#pragma unroll
        for (int s = 0; s < 4; ++s) {
            int row = s * 4 + quad;
            const float* p = &sx[w * 2112 + row * 132 + n * 8];
            float4 v0 = *(const float4*)p;
            float4 v1 = *(const float4*)(p + 4);
            uint4 o;
            o.x = pk(v0.x, v0.y); o.y = pk(v0.z, v0.w);
            o.z = pk(v1.x, v1.y); o.w = pk(v1.z, v1.w);
            int grow = t * 16 + row;
            if (grow < N) *(uint4*)&h32[(size_t)grow * 64 + n * 4] = o;
        }
    }
    // flush histogram
    if (tid < NB) {
        int c = sh[tid];
        if (c) atomicAdd(&bktCnt[tid], c);
    }
}

// ---- K2: coarse scatter into 4-aligned bucket regions; in-block scan ----
__global__ __launch_bounds__(256) void k_bucket(
        const int* __restrict__ ei, const int* __restrict__ bktCnt,
        int* __restrict__ bktCur, int* __restrict__ bktBase,
        int* __restrict__ pairs, int E, int NB) {
    __shared__ int cnt[256];
    __shared__ int gbase[256];
    __shared__ int sm[256];
    int t = threadIdx.x;
    cnt[t] = 0;
    __syncthreads();
    int base = blockIdx.x * CHUNK;
    int lim = min(CHUNK, E - base);
    const int* dsts = ei + E + base;
    const int* srcp = ei + base;
    int nv4 = lim >> 2;
    for (int i4 = t; i4 < nv4; i4 += 256) {
        int4 d4 = *(const int4*)&dsts[i4 * 4];
        atomicAdd(&cnt[d4.x >> 8], 1); atomicAdd(&cnt[d4.y >> 8], 1);
        atomicAdd(&cnt[d4.z >> 8], 1); atomicAdd(&cnt[d4.w >> 8], 1);
    }
    for (int i = nv4 * 4 + t; i < lim; i += 256)
        atomicAdd(&cnt[dsts[i] >> 8], 1);
    // exclusive scan of 4-padded global bucket counts -> aligned bases
    int bc = (t < NB) ? bktCnt[t] : 0;
    int pc = (bc + 3) & ~3;
    sm[t] = pc;
    __syncthreads();
    for (int ofs = 1; ofs < 256; ofs <<= 1) {
        int xv = (t >= ofs) ? sm[t - ofs] : 0;
        __syncthreads();
        sm[t] += xv;
        __syncthreads();
    }
    int sbase = sm[t] - pc;
    if (blockIdx.x == 0 && t < NB) bktBase[t] = sbase;
    int c = cnt[t];
    if (t < NB && c) gbase[t] = sbase + atomicAdd(&bktCur[t], c);
    __syncthreads();
    cnt[t] = 0;
    __syncthreads();
    for (int i4 = t; i4 < nv4; i4 += 256) {
        int4 s4 = *(const int4*)&srcp[i4 * 4];
        int4 d4 = *(const int4*)&dsts[i4 * 4];
        int b, r;
        b = d4.x >> 8; r = atomicAdd(&cnt[b], 1);
        pairs[gbase[b] + r] = s4.x | ((d4.x & 255) << 16);
        b = d4.y >> 8; r = atomicAdd(&cnt[b], 1);
        pairs[gbase[b] + r] = s4.y | ((d4.y & 255) << 16);
        b = d4.z >> 8; r = atomicAdd(&cnt[b], 1);
        pairs[gbase[b] + r] = s4.z | ((d4.z & 255) << 16);
        b = d4.w >> 8; r = atomicAdd(&cnt[b], 1);
        pairs[gbase[b] + r] = s4.w | ((d4.w & 255) << 16);
    }
    for (int i = nv4 * 4 + t; i < lim; i += 256) {
        int s = srcp[i], d = dsts[i];
        int b = d >> 8;
        int r = atomicAdd(&cnt[b], 1);
        pairs[gbase[b] + r] = s | ((d & 255) << 16);
    }
}

// ---- K3: fine grouping (1024 thr/bucket); rank-stash kills phase-3 atomics
__global__ __launch_bounds__(1024) void k_group(
        const int* __restrict__ bktBase, const int* __restrict__ bktCnt,
        const int* __restrict__ pairs, int* __restrict__ off,
        unsigned short* __restrict__ degw, unsigned short* __restrict__ srcs,
        int N) {
    __shared__ int cnt[256];
    __shared__ int excl[256];
    __shared__ unsigned short rnk[RCAP];
    int b = blockIdx.x, t = threadIdx.x;
    int r0 = bktBase[b];
    int ne = bktCnt[b];
    if (t < 256) cnt[t] = 0;
    __syncthreads();
    int nv4 = ne >> 2;
    bool fits = (ne <= RCAP);
    if (fits) {
        for (int i4 = t; i4 < nv4; i4 += 1024) {
            int4 p4 = *(const int4*)&pairs[r0 + i4 * 4];
            rnk[i4 * 4 + 0] = (unsigned short)atomicAdd(&cnt[p4.x >> 16], 1);
            rnk[i4 * 4 + 1] = (unsigned short)atomicAdd(&cnt[p4.y >> 16], 1);
            rnk[i4 * 4 + 2] = (unsigned short)atomicAdd(&cnt[p4.z >> 16], 1);
            rnk[i4 * 4 + 3] = (unsigned short)atomicAdd(&cnt[p4.w >> 16], 1);
        }
        for (int i = nv4 * 4 + t; i < ne; i += 1024)
            rnk[i] = (unsigned short)atomicAdd(&cnt[pairs[r0 + i] >> 16], 1);
    } else {
        for (int i = t; i < ne; i += 1024)
            atomicAdd(&cnt[pairs[r0 + i] >> 16], 1);
    }
    __syncthreads();
    int v = 0;
    if (t < 256) { v = cnt[t]; excl[t] = v; }
    __syncthreads();
    for (int ofs = 1; ofs < 256; ofs <<= 1) {
        int xv = 0;
        if (t < 256 && t >= ofs) xv = excl[t - ofs];
        __syncthreads();
        if (t < 256) excl[t] += xv;
        __syncthreads();
    }
    if (t < 256) {
        int me = excl[t] - v;
        excl[t] = me;
        int node = b * 256 + t;
        if (node < N) {
            off[node] = r0 + me;
            degw[node] = (unsigned short)v;
        }
    }
    __syncthreads();
    if (fits) {
        for (int i4 = t; i4 < nv4; i4 += 1024) {
            int4 p4 = *(const int4*)&pairs[r0 + i4 * 4];
            srcs[r0 + excl[p4.x >> 16] + rnk[i4 * 4 + 0]] = (unsigned short)(p4.x & 0xFFFF);
            srcs[r0 + excl[p4.y >> 16] + rnk[i4 * 4 + 1]] = (unsigned short)(p4.y & 0xFFFF);
            srcs[r0 + excl[p4.z >> 16] + rnk[i4 * 4 + 2]] = (unsigned short)(p4.z & 0xFFFF);
            srcs[r0 + excl[p4.w >> 16] + rnk[i4 * 4 + 3]] = (unsigned short)(p4.w & 0xFFFF);
        }
        for (int i = nv4 * 4 + t; i < ne; i += 1024) {
            int p = pairs[r0 + i];
            srcs[r0 + excl[p >> 16] + rnk[i]] = (unsigned short)(p & 0xFFFF);
        }
    } else {
        if (t < 256) cnt[t] = 0;
        __syncthreads();
        for (int i = t; i < ne; i += 1024) {
            int p = pairs[r0 + i];
            int dl = p >> 16;
            int r = atomicAdd(&cnt[dl], 1);
            srcs[r0 + excl[dl] + r] = (unsigned short)(p & 0xFFFF);
        }
    }
}

// 8-wide unrolled gather-accumulate (bf16x2 loads, fp32 accumulate)
#define GATHER8(msv, mexv, JJ)                                                 \
    {                                                                          \
        int s0 = __shfl(msv, (JJ) + 0), s1 = __shfl(msv, (JJ) + 1);            \
        int s2 = __shfl(msv, (JJ) + 2), s3 = __shfl(msv, (JJ) + 3);            \
        int s4 = __shfl(msv, (JJ) + 4), s5 = __shfl(msv, (JJ) + 5);            \
        int s6 = __shfl(msv, (JJ) + 6), s7 = __shfl(msv, (JJ) + 7);            \
        float c0 = __shfl(mexv, (JJ) + 0), c1 = __shfl(mexv, (JJ) + 1);        \
        float c2 = __shfl(mexv, (JJ) + 2), c3 = __shfl(mexv, (JJ) + 3);        \
        float c4 = __shfl(mexv, (JJ) + 4), c5 = __shfl(mexv, (JJ) + 5);        \
        float c6 = __shfl(mexv, (JJ) + 6), c7 = __shfl(mexv, (JJ) + 7);        \
        unsigned u0 = h32[(size_t)s0 * 64 + lane];                             \
        unsigned u1 = h32[(size_t)s1 * 64 + lane];                             \
        unsigned u2 = h32[(size_t)s2 * 64 + lane];                             \
        unsigned u3 = h32[(size_t)s3 * 64 + lane];                             \
        unsigned u4 = h32[(size_t)s4 * 64 + lane];                             \
        unsigned u5 = h32[(size_t)s5 * 64 + lane];                             \
        unsigned u6 = h32[(size_t)s6 * 64 + lane];                             \
        unsigned u7 = h32[(size_t)s7 * 64 + lane];                             \
        a0 += bfx(u0) * c0 + bfx(u1) * c1 + bfx(u2) * c2 + bfx(u3) * c3 +      \
              bfx(u4) * c4 + bfx(u5) * c5 + bfx(u6) * c6 + bfx(u7) * c7;       \
        a1 += bfy(u0) * c0 + bfy(u1) * c1 + bfy(u2) * c2 + bfy(u3) * c3 +      \
              bfy(u4) * c4 + bfy(u5) * c5 + bfy(u6) * c6 + bfy(u7) * c7;       \
    }

// ---- K4: one wave per dst node ----
__global__ __launch_bounds__(256) void k_agg(
        const int* __restrict__ off, const unsigned short* __restrict__ degw,
        const unsigned short* __restrict__ srcs,
        const unsigned* __restrict__ h32,
        const float* __restrict__ a_src, const float* __restrict__ a_dst,
        float* __restrict__ out, int N) {
    int node = (blockIdx.x * 256 + threadIdx.x) >> 6;
    int lane = threadIdx.x & 63;
    if (node >= N) return;
    int r0 = off[node];
    int deg = degw[node];
    float adst = a_dst[node];
    float self_al = lrelu(a_src[node] + adst);
    unsigned uself = h32[(size_t)node * 64 + lane];
    float a0, a1, inv;

    if (deg <= 64) {
        int ms = 0;
        float als = -1e30f;
        if (lane < deg) {
            ms = srcs[r0 + lane];
            als = lrelu(a_src[ms] + adst);
        }
        float m = fmaxf(self_al, als);
#pragma unroll
        for (int o = 32; o; o >>= 1) m = fmaxf(m, __shfl_xor(m, o));
        float mex = (lane < deg) ? __expf(als - m) : 0.f;
        float t = mex;
#pragma unroll
        for (int o = 32; o; o >>= 1) t += __shfl_xor(t, o);
        float eself = __expf(self_al - m);
        inv = 1.f / (t + eself + SOFT_EPS);
        a0 = bfx(uself) * eself; a1 = bfy(uself) * eself;
        int jj = 0;
        for (; jj + 8 <= deg; jj += 8) GATHER8(ms, mex, jj);
        for (; jj < deg; ++jj) {
            int s = __shfl(ms, jj);
            float cc = __shfl(mex, jj);
            unsigned u = h32[(size_t)s * 64 + lane];
            a0 += bfx(u) * cc; a1 += bfy(u) * cc;
        }
    } else {
        float m = self_al;
        for (int j = lane; j < deg; j += 64) {
            int s = srcs[r0 + j];
            m = fmaxf(m, lrelu(a_src[s] + adst));
        }
#pragma unroll
        for (int o = 32; o; o >>= 1) m = fmaxf(m, __shfl_xor(m, o));
        float eself = __expf(self_al - m);
        a0 = bfx(uself) * eself; a1 = bfy(uself) * eself;
        float t = 0.f;
        for (int c = 0; c < deg; c += 64) {
            int my = c + lane;
            int ms = (my < deg) ? (int)srcs[r0 + my] : 0;
            float mex = (my < deg) ? __expf(lrelu(a_src[ms] + adst) - m) : 0.f;
            t += mex;
            int lim = min(64, deg - c);
            int jj = 0;
            for (; jj + 8 <= lim; jj += 8) GATHER8(ms, mex, jj);
            for (; jj < lim; ++jj) {
                int s = __shfl(ms, jj);
                float cc = __shfl(mex, jj);
                unsigned u = h32[(size_t)s * 64 + lane];
                a0 += bfx(u) * cc; a1 += bfy(u) * cc;
            }
        }
#pragma unroll
        for (int o = 32; o; o >>= 1) t += __shfl_xor(t, o);
        inv = 1.f / (t + eself + SOFT_EPS);
    }
    a0 *= inv; a1 *= inv;
    *(float2*)&out[(size_t)node * DD + lane * 2] = make_float2(a0, a1);
}

extern "C" void kernel_launch(void* const* d_in, const int* in_sizes, int n_in,
                              void* d_out, int out_size, void* d_ws, size_t ws_size,
                              hipStream_t stream) {
    const float* x       = (const float*)d_in[0];
    const int*   ei      = (const int*)d_in[1];
    const float* W       = (const float*)d_in[2];
    const float* att_src = (const float*)d_in[3];
    const float* att_dst = (const float*)d_in[4];
    float* out = (float*)d_out;

    const int N = in_sizes[0] / DD;      // 50000
    const int E = in_sizes[1] / 2;       // 1600000
    const int NB = (N + 255) >> 8;       // 196
    const int ntiles = (N + 15) >> 4;    // 3125

    // ws (u32 units): h32[N*64] | a_src[N] | a_dst[N] | off[N] | degw[N u16]
    //   | bktCnt[NB] | bktCur[NB] | bktBase[256] | Wtf[8192]
    //   | pairs[E+1024] | srcs[E u16]
    unsigned* h32     = (unsigned*)d_ws;
    float*    a_src   = (float*)(h32 + (size_t)N * 64);
    float*    a_dst   = a_src + N;
    int*      off     = (int*)(a_dst + N);
    unsigned short* degw = (unsigned short*)(off + N);
    int*      bktCnt  = (int*)(degw + ((N + 1) & ~1));
    int*      bktCur  = bktCnt + NB;
    int*      bktBase = bktCur + NB;
    uint4*    Wtf4    = (uint4*)(bktBase + 256);
    int*      pairs   = (int*)(Wtf4 + 2048);
    unsigned short* srcs = (unsigned short*)(pairs + E + 1024);

    const int eblocks = (E + CHUNK - 1) / CHUNK;    // 391
    const int gblocks = (ntiles + 3) / 4;           // 782 >= eblocks

    k_wt<<<8, 256, 0, stream>>>(W, Wtf4, bktCnt, 2 * NB);
    k_gemm<<<gblocks, 256, 0, stream>>>(x, Wtf4, att_src, att_dst,
                                        h32, a_src, a_dst,
                                        ei, bktCnt, N, E, NB, eblocks, ntiles);
    k_bucket<<<eblocks, 256, 0, stream>>>(ei, bktCnt, bktCur, bktBase,
                                          pairs, E, NB);
    k_group<<<NB, 1024, 0, stream>>>(bktBase, bktCnt, pairs, off, degw,
                                     srcs, N);
    k_agg<<<(N * 64 + 255) / 256, 256, 0, stream>>>(off, degw, srcs, h32,
                                                    a_src, a_dst, out, N);
}

// Round 9
// 191.386 us; speedup vs baseline: 15.4558x; 1.0070x over previous
//
#include <hip/hip_runtime.h>
#include <math.h>

#define DD 128
#define NEG_SLOPE 0.2f
#define SOFT_EPS 1e-16f
#define CHUNK 4096    // edges per block in bucketing/histogram passes
#define RCAP 9216     // per-bucket rank-stash capacity (bucket ~8163 +- 90)
// bucket b = dst >> 8 (256 nodes); requires N <= 65536 (u16 srcs)

typedef __attribute__((ext_vector_type(8))) short short8;
typedef __attribute__((ext_vector_type(4))) float float4v;
typedef __attribute__((ext_vector_type(2))) float f2;

__device__ __forceinline__ float lrelu(float v) {
    return v >= 0.f ? v : NEG_SLOPE * v;
}
__device__ __forceinline__ unsigned f2bf(float f) {
    unsigned u = __float_as_uint(f);
    return (u + 0x7FFFu + ((u >> 16) & 1u)) >> 16;
}
__device__ __forceinline__ unsigned pk(float a, float b) {
    return f2bf(a) | (f2bf(b) << 16);
}
__device__ __forceinline__ float bfx(unsigned p) {
    return __uint_as_float(p << 16);
}
__device__ __forceinline__ float bfy(unsigned p) {
    return __uint_as_float(p & 0xFFFF0000u);
}

// ---- K0: W -> Wtf (MFMA B-fragment order) + zero bktCnt/bktCur ----
__global__ __launch_bounds__(256) void k_wt(
        const float* __restrict__ W, uint4* __restrict__ Wtf4,
        int* __restrict__ bktZero, int nz) {
    int idx = blockIdx.x * 256 + threadIdx.x;    // 2048 threads
    if (idx < nz) bktZero[idx] = 0;              // bktCnt | bktCur
    if (idx >= 2048) return;
    int g = idx >> 6, l = idx & 63;
    int ct = g >> 2, c = g & 3;
    int quad = l >> 4, n = l & 15;
    int col = ct * 16 + n;
    int k0 = c * 32 + quad * 8;
    uint4 o;
    o.x = pk(W[(k0 + 0) * DD + col], W[(k0 + 1) * DD + col]);
    o.y = pk(W[(k0 + 2) * DD + col], W[(k0 + 3) * DD + col]);
    o.z = pk(W[(k0 + 4) * DD + col], W[(k0 + 5) * DD + col]);
    o.w = pk(W[(k0 + 6) * DD + col], W[(k0 + 7) * DD + col]);
    Wtf4[idx] = o;
}

// ---- K1: h = x @ W via MFMA (x staged in LDS, fragments in-register),
//          fused node scores + fused coarse histogram ----
__global__ __launch_bounds__(256) void k_gemm(
        const float* __restrict__ x, const uint4* __restrict__ Wtf4,
        const float* __restrict__ att_src, const float* __restrict__ att_dst,
        unsigned* __restrict__ h32, float* __restrict__ a_src,
        float* __restrict__ a_dst,
        const int* __restrict__ ei, int* __restrict__ bktCnt,
        int N, int E, int NB, int eblocks, int ntiles) {
    __shared__ int sh[256];
    __shared__ float sx[64 * 132];   // 33.8 KB: x-stage, then C-tile scratch
    const int tid = threadIdx.x;
    const int w = tid >> 6;
    const int l = tid & 63;
    const int quad = l >> 4, n = l & 15;
    const int t = blockIdx.x * 4 + w;
    const bool tv = t < ntiles;

    sh[tid] = 0;
    __syncthreads();
    if ((int)blockIdx.x < eblocks) {
        int base = blockIdx.x * CHUNK;
        int lim = min(CHUNK, E - base);
        const int* dsts = ei + E + base;
        int nv4 = lim >> 2;
        for (int i4 = tid; i4 < nv4; i4 += 256) {
            int4 d4 = *(const int4*)&dsts[i4 * 4];
            atomicAdd(&sh[d4.x >> 8], 1); atomicAdd(&sh[d4.y >> 8], 1);
            atomicAdd(&sh[d4.z >> 8], 1); atomicAdd(&sh[d4.w >> 8], 1);
        }
        for (int i = nv4 * 4 + tid; i < lim; i += 256)
            atomicAdd(&sh[dsts[i] >> 8], 1);
    }

#pragma unroll
    for (int it = 0; it < 8; ++it) {
        int lin = it * 256 + tid;
        int row = lin >> 5, c4 = lin & 31;
        int grow = blockIdx.x * 64 + row;
        float4 v = make_float4(0.f, 0.f, 0.f, 0.f);
        if (grow < N) v = *(const float4*)&x[(size_t)grow * DD + c4 * 4];
        *(float4*)&sx[row * 132 + c4 * 4] = v;
    }
    __syncthreads();

    short8 af[4];
    if (tv) {
#pragma unroll
        for (int c = 0; c < 4; ++c) {
            const float* p = &sx[(w * 16 + n) * 132 + c * 32 + quad * 8];
            float4 v0 = *(const float4*)p;
            float4 v1 = *(const float4*)(p + 4);
            uint4 u;
            u.x = pk(v0.x, v0.y); u.y = pk(v0.z, v0.w);
            u.z = pk(v1.x, v1.y); u.w = pk(v1.z, v1.w);
            af[c] = __builtin_bit_cast(short8, u);
        }
    }
    __syncthreads();

    float ps[4] = {0.f, 0.f, 0.f, 0.f};
    float pd[4] = {0.f, 0.f, 0.f, 0.f};
    if (tv) {
#pragma unroll
        for (int ct = 0; ct < 8; ++ct) {
            float4v acc = {0.f, 0.f, 0.f, 0.f};
#pragma unroll
            for (int c = 0; c < 4; ++c) {
                short8 bfr = __builtin_bit_cast(short8,
                                                Wtf4[(ct * 4 + c) * 64 + l]);
                acc = __builtin_amdgcn_mfma_f32_16x16x32_bf16(af[c], bfr, acc,
                                                              0, 0, 0);
            }
            float asv = att_src[ct * 16 + n];
            float adv = att_dst[ct * 16 + n];
#pragma unroll
            for (int reg = 0; reg < 4; ++reg) {
                float v = acc[reg];
                ps[reg] += v * asv;
                pd[reg] += v * adv;
                sx[w * 2112 + (quad * 4 + reg) * 132 + ct * 16 + n] = v;
            }
        }
#pragma unroll
        for (int reg = 0; reg < 4; ++reg) {
#pragma unroll
            for (int o = 1; o < 16; o <<= 1) {
                ps[reg] += __shfl_xor(ps[reg], o);
                pd[reg] += __shfl_xor(pd[reg], o);
            }
        }
        if (n == 0) {
#pragma unroll
            for (int reg = 0; reg < 4; ++reg) {
                int grow = t * 16 + quad * 4 + reg;
                if (grow < N) { a_src[grow] = ps[reg]; a_dst[grow] = pd[reg]; }
            }
        }
    }
    __syncthreads();
    if (tv) {
#pragma unroll
        for (int s = 0; s < 4; ++s) {
            int row = s * 4 + quad;
            const float* p = &sx[w * 2112 + row * 132 + n * 8];
            float4 v0 = *(const float4*)p;
            float4 v1 = *(const float4*)(p + 4);
            uint4 o;
            o.x = pk(v0.x, v0.y); o.y = pk(v0.z, v0.w);
            o.z = pk(v1.x, v1.y); o.w = pk(v1.z, v1.w);
            int grow = t * 16 + row;
            if (grow < N) *(uint4*)&h32[(size_t)grow * 64 + n * 4] = o;
        }
    }
    if (tid < NB) {
        int c = sh[tid];
        if (c) atomicAdd(&bktCnt[tid], c);
    }
}

// ---- K2: coarse scatter into 4-aligned bucket regions; in-block scan ----
__global__ __launch_bounds__(256) void k_bucket(
        const int* __restrict__ ei, const int* __restrict__ bktCnt,
        int* __restrict__ bktCur, int* __restrict__ bktBase,
        int* __restrict__ pairs, int E, int NB) {
    __shared__ int cnt[256];
    __shared__ int gbase[256];
    __shared__ int sm[256];
    int t = threadIdx.x;
    cnt[t] = 0;
    __syncthreads();
    int base = blockIdx.x * CHUNK;
    int lim = min(CHUNK, E - base);
    const int* dsts = ei + E + base;
    const int* srcp = ei + base;
    int nv4 = lim >> 2;
    for (int i4 = t; i4 < nv4; i4 += 256) {
        int4 d4 = *(const int4*)&dsts[i4 * 4];
        atomicAdd(&cnt[d4.x >> 8], 1); atomicAdd(&cnt[d4.y >> 8], 1);
        atomicAdd(&cnt[d4.z >> 8], 1); atomicAdd(&cnt[d4.w >> 8], 1);
    }
    for (int i = nv4 * 4 + t; i < lim; i += 256)
        atomicAdd(&cnt[dsts[i] >> 8], 1);
    int bc = (t < NB) ? bktCnt[t] : 0;
    int pc = (bc + 3) & ~3;
    sm[t] = pc;
    __syncthreads();
    for (int ofs = 1; ofs < 256; ofs <<= 1) {
        int xv = (t >= ofs) ? sm[t - ofs] : 0;
        __syncthreads();
        sm[t] += xv;
        __syncthreads();
    }
    int sbase = sm[t] - pc;
    if (blockIdx.x == 0 && t < NB) bktBase[t] = sbase;
    int c = cnt[t];
    if (t < NB && c) gbase[t] = sbase + atomicAdd(&bktCur[t], c);
    __syncthreads();
    cnt[t] = 0;
    __syncthreads();
    for (int i4 = t; i4 < nv4; i4 += 256) {
        int4 s4 = *(const int4*)&srcp[i4 * 4];
        int4 d4 = *(const int4*)&dsts[i4 * 4];
        int b, r;
        b = d4.x >> 8; r = atomicAdd(&cnt[b], 1);
        pairs[gbase[b] + r] = s4.x | ((d4.x & 255) << 16);
        b = d4.y >> 8; r = atomicAdd(&cnt[b], 1);
        pairs[gbase[b] + r] = s4.y | ((d4.y & 255) << 16);
        b = d4.z >> 8; r = atomicAdd(&cnt[b], 1);
        pairs[gbase[b] + r] = s4.z | ((d4.z & 255) << 16);
        b = d4.w >> 8; r = atomicAdd(&cnt[b], 1);
        pairs[gbase[b] + r] = s4.w | ((d4.w & 255) << 16);
    }
    for (int i = nv4 * 4 + t; i < lim; i += 256) {
        int s = srcp[i], d = dsts[i];
        int b = d >> 8;
        int r = atomicAdd(&cnt[b], 1);
        pairs[gbase[b] + r] = s | ((d & 255) << 16);
    }
}

// ---- K3: fine grouping (1024 thr/bucket); rank-stash kills phase-3 atomics
__global__ __launch_bounds__(1024) void k_group(
        const int* __restrict__ bktBase, const int* __restrict__ bktCnt,
        const int* __restrict__ pairs, int* __restrict__ off,
        unsigned short* __restrict__ degw, unsigned short* __restrict__ srcs,
        int N) {
    __shared__ int cnt[256];
    __shared__ int excl[256];
    __shared__ unsigned short rnk[RCAP];
    int b = blockIdx.x, t = threadIdx.x;
    int r0 = bktBase[b];
    int ne = bktCnt[b];
    if (t < 256) cnt[t] = 0;
    __syncthreads();
    int nv4 = ne >> 2;
    bool fits = (ne <= RCAP);
    if (fits) {
        for (int i4 = t; i4 < nv4; i4 += 1024) {
            int4 p4 = *(const int4*)&pairs[r0 + i4 * 4];
            rnk[i4 * 4 + 0] = (unsigned short)atomicAdd(&cnt[p4.x >> 16], 1);
            rnk[i4 * 4 + 1] = (unsigned short)atomicAdd(&cnt[p4.y >> 16], 1);
            rnk[i4 * 4 + 2] = (unsigned short)atomicAdd(&cnt[p4.z >> 16], 1);
            rnk[i4 * 4 + 3] = (unsigned short)atomicAdd(&cnt[p4.w >> 16], 1);
        }
        for (int i = nv4 * 4 + t; i < ne; i += 1024)
            rnk[i] = (unsigned short)atomicAdd(&cnt[pairs[r0 + i] >> 16], 1);
    } else {
        for (int i = t; i < ne; i += 1024)
            atomicAdd(&cnt[pairs[r0 + i] >> 16], 1);
    }
    __syncthreads();
    int v = 0;
    if (t < 256) { v = cnt[t]; excl[t] = v; }
    __syncthreads();
    for (int ofs = 1; ofs < 256; ofs <<= 1) {
        int xv = 0;
        if (t < 256 && t >= ofs) xv = excl[t - ofs];
        __syncthreads();
        if (t < 256) excl[t] += xv;
        __syncthreads();
    }
    if (t < 256) {
        int me = excl[t] - v;
        excl[t] = me;
        int node = b * 256 + t;
        if (node < N) {
            off[node] = r0 + me;
            degw[node] = (unsigned short)v;
        }
    }
    __syncthreads();
    if (fits) {
        for (int i4 = t; i4 < nv4; i4 += 1024) {
            int4 p4 = *(const int4*)&pairs[r0 + i4 * 4];
            srcs[r0 + excl[p4.x >> 16] + rnk[i4 * 4 + 0]] = (unsigned short)(p4.x & 0xFFFF);
            srcs[r0 + excl[p4.y >> 16] + rnk[i4 * 4 + 1]] = (unsigned short)(p4.y & 0xFFFF);
            srcs[r0 + excl[p4.z >> 16] + rnk[i4 * 4 + 2]] = (unsigned short)(p4.z & 0xFFFF);
            srcs[r0 + excl[p4.w >> 16] + rnk[i4 * 4 + 3]] = (unsigned short)(p4.w & 0xFFFF);
        }
        for (int i = nv4 * 4 + t; i < ne; i += 1024) {
            int p = pairs[r0 + i];
            srcs[r0 + excl[p >> 16] + rnk[i]] = (unsigned short)(p & 0xFFFF);
        }
    } else {
        if (t < 256) cnt[t] = 0;
        __syncthreads();
        for (int i = t; i < ne; i += 1024) {
            int p = pairs[r0 + i];
            int dl = p >> 16;
            int r = atomicAdd(&cnt[dl], 1);
            srcs[r0 + excl[dl] + r] = (unsigned short)(p & 0xFFFF);
        }
    }
}

// slow-path 8-wide gather (shfl-broadcast; only for rare deg>64 nodes)
#define GATHER8(msv, mexv, JJ)                                                 \
    {                                                                          \
        int s0 = __shfl(msv, (JJ) + 0), s1 = __shfl(msv, (JJ) + 1);            \
        int s2 = __shfl(msv, (JJ) + 2), s3 = __shfl(msv, (JJ) + 3);            \
        int s4 = __shfl(msv, (JJ) + 4), s5 = __shfl(msv, (JJ) + 5);            \
        int s6 = __shfl(msv, (JJ) + 6), s7 = __shfl(msv, (JJ) + 7);            \
        float c0 = __shfl(mexv, (JJ) + 0), c1 = __shfl(mexv, (JJ) + 1);        \
        float c2 = __shfl(mexv, (JJ) + 2), c3 = __shfl(mexv, (JJ) + 3);        \
        float c4 = __shfl(mexv, (JJ) + 4), c5 = __shfl(mexv, (JJ) + 5);        \
        float c6 = __shfl(mexv, (JJ) + 6), c7 = __shfl(mexv, (JJ) + 7);        \
        unsigned u0 = h32[(size_t)s0 * 64 + lane];                             \
        unsigned u1 = h32[(size_t)s1 * 64 + lane];                             \
        unsigned u2 = h32[(size_t)s2 * 64 + lane];                             \
        unsigned u3 = h32[(size_t)s3 * 64 + lane];                             \
        unsigned u4 = h32[(size_t)s4 * 64 + lane];                             \
        unsigned u5 = h32[(size_t)s5 * 64 + lane];                             \
        unsigned u6 = h32[(size_t)s6 * 64 + lane];                             \
        unsigned u7 = h32[(size_t)s7 * 64 + lane];                             \
        a0 += bfx(u0) * c0 + bfx(u1) * c1 + bfx(u2) * c2 + bfx(u3) * c3 +      \
              bfx(u4) * c4 + bfx(u5) * c5 + bfx(u6) * c6 + bfx(u7) * c7;       \
        a1 += bfy(u0) * c0 + bfy(u1) * c1 + bfy(u2) * c2 + bfy(u3) * c3 +      \
              bfy(u4) * c4 + bfy(u5) * c5 + bfy(u6) * c6 + bfy(u7) * c7;       \
    }

// fast-path batched gather: addresses/coefs from per-wave LDS (uniform
// ds_read broadcast), 8 loads per batch, two batches in flight
#define FETCH8(U, JJ)                                                          \
    {                                                                          \
        _Pragma("unroll") for (int j = 0; j < 8; ++j) {                        \
            unsigned mb = sA[swb + (JJ) + j];                                  \
            U[j] = h32[mb + (unsigned)lane];                                   \
        }                                                                      \
    }
#define CONSUME8(U, JJ)                                                        \
    {                                                                          \
        _Pragma("unroll") for (int j = 0; j < 8; ++j) {                        \
            float cj = sB[swb + (JJ) + j];                                     \
            f2 hv = {bfx(U[j]), bfy(U[j])};                                    \
            f2 cv = {cj, cj};                                                  \
            acc = __builtin_elementwise_fma(hv, cv, acc);                      \
        }                                                                      \
    }

// ---- K4: one wave per dst node ----
__global__ __launch_bounds__(256) void k_agg(
        const int* __restrict__ off, const unsigned short* __restrict__ degw,
        const unsigned short* __restrict__ srcs,
        const unsigned* __restrict__ h32,
        const float* __restrict__ a_src, const float* __restrict__ a_dst,
        float* __restrict__ out, int N) {
    __shared__ unsigned sA[4 * 64];   // per-wave: src row base (element idx)
    __shared__ float sB[4 * 64];      // per-wave: exp coefficient
    int node = (blockIdx.x * 256 + threadIdx.x) >> 6;
    int lane = threadIdx.x & 63;
    int swb = (threadIdx.x >> 6) * 64;
    if (node >= N) return;
    int r0 = off[node];
    int deg = degw[node];
    float adst = a_dst[node];
    float self_al = lrelu(a_src[node] + adst);
    unsigned uself = h32[(size_t)node * 64 + lane];
    float a0, a1, inv;

    if (deg <= 64) {
        int ms = 0;
        float als = -1e30f;
        if (lane < deg) {
            ms = srcs[r0 + lane];
            als = lrelu(a_src[ms] + adst);
        }
        float m = fmaxf(self_al, als);
#pragma unroll
        for (int o = 32; o; o >>= 1) m = fmaxf(m, __shfl_xor(m, o));
        float mex = (lane < deg) ? __expf(als - m) : 0.f;
        float t = mex;
#pragma unroll
        for (int o = 32; o; o >>= 1) t += __shfl_xor(t, o);
        float eself = __expf(self_al - m);
        inv = 1.f / (t + eself + SOFT_EPS);
        // stage (row base, coef) in per-wave LDS; dummy rows get coef 0
        sA[swb + lane] = (lane < deg) ? ((unsigned)ms << 6) : 0u;
        sB[swb + lane] = mex;
        f2 acc = {bfx(uself) * eself, bfy(uself) * eself};
        int degp = (deg + 7) & ~7;    // padded: batches always full
        int jj = 0;
        for (; jj + 16 <= degp; jj += 16) {
            unsigned uA[8], uB[8];
            FETCH8(uA, jj);
            FETCH8(uB, jj + 8);
            CONSUME8(uA, jj);
            CONSUME8(uB, jj + 8);
        }
        if (jj < degp) {
            unsigned uA[8];
            FETCH8(uA, jj);
            CONSUME8(uA, jj);
        }
        a0 = acc.x; a1 = acc.y;
    } else {
        float m = self_al;
        for (int j = lane; j < deg; j += 64) {
            int s = srcs[r0 + j];
            m = fmaxf(m, lrelu(a_src[s] + adst));
        }
#pragma unroll
        for (int o = 32; o; o >>= 1) m = fmaxf(m, __shfl_xor(m, o));
        float eself = __expf(self_al - m);
        a0 = bfx(uself) * eself; a1 = bfy(uself) * eself;
        float t = 0.f;
        for (int c = 0; c < deg; c += 64) {
            int my = c + lane;
            int ms = (my < deg) ? (int)srcs[r0 + my] : 0;
            float mex = (my < deg) ? __expf(lrelu(a_src[ms] + adst) - m) : 0.f;
            t += mex;
            int lim = min(64, deg - c);
            int jj = 0;
            for (; jj + 8 <= lim; jj += 8) GATHER8(ms, mex, jj);
            for (; jj < lim; ++jj) {
                int s = __shfl(ms, jj);
                float cc = __shfl(mex, jj);
                unsigned u = h32[(size_t)s * 64 + lane];
                a0 += bfx(u) * cc; a1 += bfy(u) * cc;
            }
        }
#pragma unroll
        for (int o = 32; o; o >>= 1) t += __shfl_xor(t, o);
        inv = 1.f / (t + eself + SOFT_EPS);
    }
    a0 *= inv; a1 *= inv;
    *(float2*)&out[(size_t)node * DD + lane * 2] = make_float2(a0, a1);
}

extern "C" void kernel_launch(void* const* d_in, const int* in_sizes, int n_in,
                              void* d_out, int out_size, void* d_ws, size_t ws_size,
                              hipStream_t stream) {
    const float* x       = (const float*)d_in[0];
    const int*   ei      = (const int*)d_in[1];
    const float* W       = (const float*)d_in[2];
    const float* att_src = (const float*)d_in[3];
    const float* att_dst = (const float*)d_in[4];
    float* out = (float*)d_out;

    const int N = in_sizes[0] / DD;      // 50000
    const int E = in_sizes[1] / 2;       // 1600000
    const int NB = (N + 255) >> 8;       // 196
    const int ntiles = (N + 15) >> 4;    // 3125

    unsigned* h32     = (unsigned*)d_ws;
    float*    a_src   = (float*)(h32 + (size_t)N * 64);
    float*    a_dst   = a_src + N;
    int*      off     = (int*)(a_dst + N);
    unsigned short* degw = (unsigned short*)(off + N);
    int*      bktCnt  = (int*)(degw + ((N + 1) & ~1));
    int*      bktCur  = bktCnt + NB;
    int*      bktBase = bktCur + NB;
    uint4*    Wtf4    = (uint4*)(bktBase + 256);
    int*      pairs   = (int*)(Wtf4 + 2048);
    unsigned short* srcs = (unsigned short*)(pairs + E + 1024);

    const int eblocks = (E + CHUNK - 1) / CHUNK;    // 391
    const int gblocks = (ntiles + 3) / 4;           // 782 >= eblocks

    k_wt<<<8, 256, 0, stream>>>(W, Wtf4, bktCnt, 2 * NB);
    k_gemm<<<gblocks, 256, 0, stream>>>(x, Wtf4, att_src, att_dst,
                                        h32, a_src, a_dst,
                                        ei, bktCnt, N, E, NB, eblocks, ntiles);
    k_bucket<<<eblocks, 256, 0, stream>>>(ei, bktCnt, bktCur, bktBase,
                                          pairs, E, NB);
    k_group<<<NB, 1024, 0, stream>>>(bktBase, bktCnt, pairs, off, degw,
                                     srcs, N);
    k_agg<<<(N * 64 + 255) / 256, 256, 0, stream>>>(off, degw, srcs, h32,
                                                    a_src, a_dst, out, N);
}